// Round 6
// baseline (219.464 us; speedup 1.0000x reference)
//
#include <hip/hip_runtime.h>

typedef __attribute__((ext_vector_type(8))) short short8;
typedef __attribute__((ext_vector_type(4))) float f32x4;
typedef __attribute__((ext_vector_type(2))) int int2v;
typedef __attribute__((ext_vector_type(4))) int int4v;

__device__ __forceinline__ short f2bf(float f) {
  unsigned u = __builtin_bit_cast(unsigned, f);
  u += 0x7fff + ((u >> 16) & 1);  // RNE
  return (short)(u >> 16);
}

__device__ __forceinline__ int pk2bf(float lo, float hi) {
#if defined(__gfx950__) && __has_builtin(__builtin_amdgcn_cvt_pk_bf16_f32)
  typedef __attribute__((ext_vector_type(2))) __bf16 bf16x2;
  bf16x2 v = __builtin_amdgcn_cvt_pk_bf16_f32(lo, hi);
  return __builtin_bit_cast(int, v);
#else
  return (int)(unsigned short)(short)f2bf(lo) | (((int)f2bf(hi)) << 16);
#endif
}

// truncating pack; r17: single v_perm_b32 (was lshr+and+or). Bias cancels through
// p/l normalization (l sums the same truncated p via the ones-MFMA).
__device__ __forceinline__ int pktr(float lo, float hi) {
#if __has_builtin(__builtin_amdgcn_perm)
  return (int)__builtin_amdgcn_perm(__builtin_bit_cast(unsigned, hi),
                                    __builtin_bit_cast(unsigned, lo), 0x07060302u);
#else
  return (int)(__builtin_bit_cast(unsigned, lo) >> 16) |
         (int)(__builtin_bit_cast(unsigned, hi) & 0xffff0000u);
#endif
}

__device__ __forceinline__ short8 pack8(f32x4 a, f32x4 b) {
  int4v t;
  t.x = pk2bf(a[0], a[1]);
  t.y = pk2bf(a[2], a[3]);
  t.z = pk2bf(b[0], b[1]);
  t.w = pk2bf(b[2], b[3]);
  return __builtin_bit_cast(short8, t);
}

__device__ __forceinline__ float fand(float p, int m) {
  return __builtin_bit_cast(float, __builtin_bit_cast(int, p) & m);
}

__device__ __forceinline__ int bmask(unsigned w, int bit) {
#if __has_builtin(__builtin_amdgcn_sbfe)
  return __builtin_amdgcn_sbfe((int)w, bit, 1);  // 0 or -1
#else
  return ((int)(w << (31 - bit))) >> 31;
#endif
}

__device__ __forceinline__ float fexp2(float x) {
#if __has_builtin(__builtin_amdgcn_exp2f)
  return __builtin_amdgcn_exp2f(x);
#else
  return exp2f(x);
#endif
}

// async global->LDS, 16B per lane; LDS dest = wave-uniform base + lane*16
__device__ __forceinline__ void glds16(const short* g, short* lbase, int lane) {
#if __has_builtin(__builtin_amdgcn_global_load_lds)
  __builtin_amdgcn_global_load_lds(
      (const __attribute__((address_space(1))) unsigned int*)g,
      (__attribute__((address_space(3))) unsigned int*)lbase, 16, 0, 0);
#else
  *(short8*)(lbase + lane * 8) = *(const short8*)g;
#endif
}

// =============== projqkv: Q/K/V projections (r17: split out of prep) ===============
// sigma'(grp*16 + qk*4 + r) = qk*8 + (grp&1)*4 + r + (grp>>1)*32 for V (in-reg-P flash).
__global__ __launch_bounds__(256) void projqkv(const float* __restrict__ q,
                                               const float* __restrict__ k,
                                               const float* __restrict__ v,
                                               const float* __restrict__ Wq,
                                               const float* __restrict__ Wk,
                                               const float* __restrict__ Wv,
                                               short* __restrict__ Qp,
                                               short* __restrict__ Kp,
                                               short* __restrict__ Vtp) {
  const int bid = blockIdx.x;
  const int tid = threadIdx.x;

  __shared__ short xt[64][72];
  __shared__ short ot[64][72];
  const int mode = bid >> 10;
  const int bt = bid & 1023;
  const float* X;
  const float* W;
  float scale;
  if (mode == 0) { X = q; W = Wq; scale = 0.045084220f; }  // log2(e)/32 folded into Q
  else if (mode == 1) { X = k; W = Wk; scale = 1.0f; }
  else { X = v; W = Wv; scale = 1.0f; }

  const int r0 = bt * 64;
  const int row = tid >> 2, seg = (tid & 3) * 16;
  const f32x4* xs = (const f32x4*)(X + (r0 + row) * 64 + seg);
  const f32x4 x0 = xs[0], x1 = xs[1], x2 = xs[2], x3 = xs[3];
  *(short8*)&xt[row][seg] = pack8(x0, x1);
  *(short8*)&xt[row][seg + 8] = pack8(x2, x3);
  __syncthreads();

  const int lane = tid & 63, wave = tid >> 6;
  const int m16 = lane & 15, quad = lane >> 4;

  const short8 a0 = *(const short8*)&xt[wave * 16 + m16][quad * 8];
  const short8 a1 = *(const short8*)&xt[wave * 16 + m16][32 + quad * 8];

  f32x4 acc[4];
#pragma unroll
  for (int nt = 0; nt < 4; ++nt) {
    const f32x4* wp0 = (const f32x4*)&W[(nt * 16 + m16) * 64 + quad * 8];
    const f32x4* wp1 = (const f32x4*)&W[(nt * 16 + m16) * 64 + 32 + quad * 8];
    const short8 b0 = pack8(wp0[0], wp0[1]);
    const short8 b1 = pack8(wp1[0], wp1[1]);
    f32x4 z = (f32x4){0.f, 0.f, 0.f, 0.f};
    z = __builtin_amdgcn_mfma_f32_16x16x32_bf16(a0, b0, z, 0, 0, 0);
    z = __builtin_amdgcn_mfma_f32_16x16x32_bf16(a1, b1, z, 0, 0, 0);
    acc[nt] = z;
  }

  if (mode != 2) {
#pragma unroll
    for (int nt = 0; nt < 4; ++nt)
#pragma unroll
      for (int r = 0; r < 4; ++r)
        ot[wave * 16 + quad * 4 + r][nt * 16 + m16] = f2bf(acc[nt][r] * scale);
  } else {
    // transposed + sigma'-permuted: ot[d][sigma'(key)],
    // key = wave*16 + quad*4 + r -> sigma' = quad*8 + (wave&1)*4 + r + (wave>>1)*32
#pragma unroll
    for (int nt = 0; nt < 4; ++nt)
#pragma unroll
      for (int r = 0; r < 4; ++r)
        ot[nt * 16 + m16][quad * 8 + (wave & 1) * 4 + r + (wave >> 1) * 32] =
            f2bf(acc[nt][r]);
  }
  __syncthreads();

  const int orow = tid >> 2, opart = tid & 3;
  if (mode != 2) {
    short* dst = (mode == 0 ? Qp : Kp) + (r0 + orow) * 64 + opart * 16;
    *(short8*)&dst[0] = *(const short8*)&ot[orow][opart * 16];
    *(short8*)&dst[8] = *(const short8*)&ot[orow][opart * 16 + 8];
  } else {
    const int bh = r0 >> 11, s0 = r0 & 2047;
    short* dst = Vtp + bh * 131072 + orow * 2048 + s0 + opart * 16;
    *(short8*)&dst[0] = *(const short8*)&ot[orow][opart * 16];
    *(short8*)&dst[8] = *(const short8*)&ot[orow][opart * 16 + 8];
  }
}

// =============== maskwo: packed mask table (coalesced) + Wo convert ===============
// r17: the r15 mask pass read 32 SCALAR loads/thread with the lane index on the ROW
// (stride 8KB) — fully uncoalesced over 33.5 MB. Rewritten as LDS transpose:
// phase 1: 8 int4/thread, coalesced (512B per 32-lane row-slab), packed to 0/1 BYTES
// in an XOR-swizzled [64][128] LDS bitboard (write & read verified <=2-way banks);
// phase 2: 8 ds_read_b32/thread + (w&0x01010101)*0x01020408>>24 nibble-pack.
// Bit layout identical to r15: bit[hb*16+grp*4+r] for q-row(wv,m16), col(hb,grp,qd,r).
__global__ __launch_bounds__(256) void maskwo(const int* __restrict__ mask,
                                              const float* __restrict__ Wo,
                                              short* __restrict__ Wob,
                                              unsigned* __restrict__ mmod) {
  const int bid = blockIdx.x;
  const int tid = threadIdx.x;

  if (bid >= 1024) {  // ---- Wo convert ----
    const int i = ((bid - 1024) * 256 + tid) * 4;
    const f32x4 x = *(const f32x4*)&Wo[i];
    int2v o;
    o.x = pk2bf(x[0], x[1]);
    o.y = pk2bf(x[2], x[3]);
    *(int2v*)&Wob[i] = o;
    return;
  }

  __shared__ __attribute__((aligned(16))) unsigned char mbits[8192];  // [64 rows][128 cols]
  const int mb = bid;  // (b*32+q64)*16 + kp
  const int kp = mb & 15, bq = mb >> 4;
  const int b_ = bq >> 5, q64 = bq & 31;
  const int* msrc = mask + b_ * 4194304 + q64 * 64 * 2048 + kp * 128;

  // phase 1: coalesced int4 loads -> 0/1 bytes into swizzled LDS
#pragma unroll
  for (int i = 0; i < 8; ++i) {
    const int idx = tid + i * 256;      // int4 index within the 64x128 region
    const int row = idx >> 5;
    const int col = (idx * 4) & 127;    // int column (== byte column)
    const int4v x = *(const int4v*)(msrc + row * 2048 + col);
    // mask values are 0/1 (randint 0..2) -> low bytes are the values
    const unsigned w = (unsigned)x.x | ((unsigned)x.y << 8) |
                       ((unsigned)x.z << 16) | ((unsigned)x.w << 24);
    *(unsigned*)(mbits + row * 128 + (col ^ ((row & 7) << 4))) = w;
  }
  __syncthreads();

  // phase 2: gather 32 bits per output entry (tid' == flash lane mapping)
  const int wv = tid >> 6, qd = (tid >> 4) & 3, m16_ = tid & 15;
  const int row = wv * 16 + m16_;
  const int swz = (row & 7) << 4;
  const unsigned char* rb = mbits + row * 128;
  unsigned d = 0;
#pragma unroll
  for (int hb = 0; hb < 2; ++hb)
#pragma unroll
    for (int grp = 0; grp < 4; ++grp) {
      const unsigned w =
          *(const unsigned*)(rb + ((hb * 64 + grp * 16 + qd * 4) ^ swz));
      const unsigned nib = (((w & 0x01010101u) * 0x01020408u) >> 24) & 0xFu;
      d |= nib << (hb * 16 + grp * 4);
    }
  mmod[mb * 256 + tid] = d;
}

// =============== flash64r: 64 q-rows, in-register P, l via ones-MFMA ===============
// r17 on r16 (64.5 us, MfmaUtil 24, VALUBusy 58 — VALU is the top pipe):
//  (a) pktr via v_perm_b32 (1 op vs 3; -16 VALU/tile/wave)
//  (b) koff/koffx (=koff^64) hoisted so every K/V ds_read is base+imm (grp*2048)
// Structure unchanged: swapped-QK in-reg P, 2 barriers/tile, counted vmcnt(5)/(5),
// peel (4)/(0), 32KB LDS, epilogue via kt0.
__global__ __launch_bounds__(256) void flash64r(const short* __restrict__ Qp,
                                                const short* __restrict__ Kp,
                                                const short* __restrict__ Vt,
                                                const unsigned* __restrict__ mmod,
                                                short* __restrict__ Ob) {
  __shared__ __attribute__((aligned(16))) short kt0[4096];
  __shared__ __attribute__((aligned(16))) short kt1[4096];
  __shared__ __attribute__((aligned(16))) short vt0[4096];
  __shared__ __attribute__((aligned(16))) short vt1[4096];
  const int tid = threadIdx.x;
  const int bid = blockIdx.x;
  const int local = bid >> 3;  // XCD-grouping on bid&7
  const int qblk = local & 31;
  const int bh = (bid & 7) * 4 + (local >> 5);
  const int q0 = qblk << 6;
  const int b = bh >> 4;
  const short* Qh = Qp + bh * 131072;
  const short* Kh = Kp + bh * 131072;
  const short* Vh = Vt + bh * 131072;
  const int lane = tid & 63, wave = tid >> 6;
  const int m16 = lane & 15, quad = lane >> 4;
  const int srow = lane >> 3, sj = (lane & 7) ^ srow;
  const int koff = m16 * 128 + ((quad ^ (m16 & 7)) * 16);
  const int koffx = koff ^ 64;
  // per-lane mask dword: table tid' = wave*64 + lane; one dword per kp (2 tiles)
  const unsigned* mq = mmod + ((b * 32 + qblk) * 16) * 256 + wave * 64 + quad * 16 + m16;

  const short onebf = (short)0x3F80;  // bf16 1.0
  const short8 ones = (short8){onebf, onebf, onebf, onebf, onebf, onebf, onebf, onebf};

  short8 aq[2];
#pragma unroll
  for (int h = 0; h < 2; ++h)
    aq[h] = *(const short8*)&Qh[(q0 + wave * 16 + m16) * 64 + h * 32 + quad * 8];

  f32x4 oaccL = (f32x4){0.f, 0.f, 0.f, 0.f};  // row-sum accumulator (l)
  f32x4 oacc[4];
#pragma unroll
  for (int dt = 0; dt < 4; ++dt) oacc[dt] = (f32x4){0.f, 0.f, 0.f, 0.f};

  // stage 64-key tile ka into (ktb, vtb); 4 glds16 per wave (+4 vmcnt)
  auto stage = [&](short* ktb, short* vtb, int ka) {
#pragma unroll
    for (int t = 0; t < 2; ++t) {
      const int crow = wave * 16 + t * 8;
      glds16(Kh + (ka * 64 + crow + srow) * 64 + sj * 8, ktb + crow * 64, lane);
      glds16(Vh + (crow + srow) * 2048 + ka * 64 + sj * 8, vtb + crow * 64, lane);
    }
  };

  // full tile: swapped QK^T -> in-register P -> PV (+ l via ones-MFMA). No LDS writes.
  auto compute = [&](const short* ktp, const short* vtp, unsigned mw, int bb) {
    const char* kb_lo = (const char*)ktp + koff;
    const char* kb_hi = (const char*)ktp + koffx;
    const char* vb_lo = (const char*)vtp + koff;
    const char* vb_hi = (const char*)vtp + koffx;
    // S^T quadrants: s[grp][r] = S[q = m16][key = grp*16 + quad*4 + r]
    f32x4 s[4];
    __builtin_amdgcn_s_setprio(1);
#pragma unroll
    for (int grp = 0; grp < 4; ++grp) {
      const short8 kb0 = *(const short8*)(kb_lo + grp * 2048);
      const short8 kb1 = *(const short8*)(kb_hi + grp * 2048);
      f32x4 z = (f32x4){0.f, 0.f, 0.f, 0.f};
      z = __builtin_amdgcn_mfma_f32_16x16x32_bf16(kb0, aq[0], z, 0, 0, 0);
      z = __builtin_amdgcn_mfma_f32_16x16x32_bf16(kb1, aq[1], z, 0, 0, 0);
      s[grp] = z;
    }
    __builtin_amdgcn_s_setprio(0);

    // p = exp2(s) & mask-bit (all 16 p's belong to q = m16)
    float p[4][4];
#pragma unroll
    for (int grp = 0; grp < 4; ++grp)
#pragma unroll
      for (int r = 0; r < 4; ++r)
        p[grp][r] = fand(fexp2(s[grp][r]), bmask(mw, bb + grp * 4 + r));

    // pack P into the PV A-fragments directly (sigma' makes these the lane's slots)
    int4v t0, t1;
    t0.x = pktr(p[0][0], p[0][1]);
    t0.y = pktr(p[0][2], p[0][3]);
    t0.z = pktr(p[1][0], p[1][1]);
    t0.w = pktr(p[1][2], p[1][3]);
    t1.x = pktr(p[2][0], p[2][1]);
    t1.y = pktr(p[2][2], p[2][3]);
    t1.z = pktr(p[3][0], p[3][1]);
    t1.w = pktr(p[3][2], p[3][3]);
    const short8 ap0 = __builtin_bit_cast(short8, t0);
    const short8 ap1 = __builtin_bit_cast(short8, t1);

    // O += P V; l += P·1 (matrix pipe; no LDS dep -> issues while vb reads land)
    __builtin_amdgcn_s_setprio(1);
    oaccL = __builtin_amdgcn_mfma_f32_16x16x32_bf16(ap0, ones, oaccL, 0, 0, 0);
    oaccL = __builtin_amdgcn_mfma_f32_16x16x32_bf16(ap1, ones, oaccL, 0, 0, 0);
#pragma unroll
    for (int dt = 0; dt < 4; ++dt) {
      const short8 vb0 = *(const short8*)(vb_lo + dt * 2048);
      const short8 vb1 = *(const short8*)(vb_hi + dt * 2048);
      f32x4 z = oacc[dt];
      z = __builtin_amdgcn_mfma_f32_16x16x32_bf16(ap0, vb0, z, 0, 0, 0);
      z = __builtin_amdgcn_mfma_f32_16x16x32_bf16(ap1, vb1, z, 0, 0, 0);
      oacc[dt] = z;
    }
    __builtin_amdgcn_s_setprio(0);
  };

  // ---- prologue: mask for kp=0, both stages; first waitA covers aq+M0+S0 ----
  unsigned mw = mq[0];
  stage(kt0, vt0, 0);
  stage(kt1, vt1, 1);

  for (int kk = 0; kk < 15; ++kk) {
    const unsigned mwn = mq[(kk + 1) * 256];
    // tile A = 2kk (buf0): drain M(kk)+S(2kk); newer = S(2kk+1)[4] + M(kk+1)[1]
    asm volatile("s_waitcnt vmcnt(5)" ::: "memory");
    __builtin_amdgcn_s_barrier();
    compute(kt0, vt0, mw, 0);
    __builtin_amdgcn_s_barrier();  // done reading buf0
    stage(kt0, vt0, 2 * kk + 2);
    // tile B = 2kk+1 (buf1): drain S(2kk+1); newer = M(kk+1)[1] + S(2kk+2)[4]
    asm volatile("s_waitcnt vmcnt(5)" ::: "memory");
    __builtin_amdgcn_s_barrier();
    compute(kt1, vt1, mw, 16);
    __builtin_amdgcn_s_barrier();  // done reading buf1
    stage(kt1, vt1, 2 * kk + 3);
    mw = mwn;
  }
  // peeled kk=15: outstanding [M15(1), S30(4), S31(4)]
  asm volatile("s_waitcnt vmcnt(4)" ::: "memory");
  __builtin_amdgcn_s_barrier();
  compute(kt0, vt0, mw, 0);
  asm volatile("s_waitcnt vmcnt(0)" ::: "memory");
  __builtin_amdgcn_s_barrier();
  compute(kt1, vt1, mw, 16);

  // ---- epilogue ----
  // l[q = quad*4 + r] = oaccL[r] on every lane (ones-B makes all 16 cols equal)
  float linv[4];
#pragma unroll
  for (int r = 0; r < 4; ++r) linv[r] = 1.0f / oaccL[r];

  // normalize, write O (bf16) into kt0 (swizzled; wave-private rows — safe: all
  // cross-wave kt0 reads finished before the barrier preceding compute(kt1))
  char* const ptB = (char*)kt0;
#pragma unroll
  for (int r = 0; r < 4; ++r) {
    const int row = wave * 16 + quad * 4 + r;
#pragma unroll
    for (int dt = 0; dt < 4; ++dt)
      *(short*)(ptB + row * 128 + ((dt * 32 + m16 * 2) ^ ((row & 7) << 4))) =
          f2bf(oacc[dt][r] * linv[r]);
  }
  asm volatile("s_waitcnt lgkmcnt(0)" ::: "memory");  // same-wave rows: no barrier

  // coalesced O store (rows partitioned within the wave)
  const int orow = lane >> 2, opart = lane & 3;
  const int prow = wave * 16 + orow;
  const int oswz = (orow & 7) << 4;
  short* og = Ob + (bh * 2048 + q0 + prow) * 64 + opart * 16;
  *(short8*)&og[0] = *(const short8*)(ptB + prow * 128 + ((opart * 32) ^ oswz));
  *(short8*)&og[8] = *(const short8*)(ptB + prow * 128 + ((opart * 32 + 16) ^ oswz));
}

// =============== outproj: out = Ob @ Wo^T + bo, 64x128 tiles, pipelined ===============
// r16 structure (unchanged): glds16 staging, row-XOR swizzle, double-buffer,
// counted vmcnt(6), peel 6/0. LDS 48KB, 2 blocks/CU.
__global__ __launch_bounds__(256) void outproj(const short* __restrict__ Ob,
                                               const short* __restrict__ Wob,
                                               const float* __restrict__ bo,
                                               float* __restrict__ out) {
  __shared__ __attribute__((aligned(16))) short at0[4096];
  __shared__ __attribute__((aligned(16))) short at1[4096];
  __shared__ __attribute__((aligned(16))) short bt0[8192];
  __shared__ __attribute__((aligned(16))) short bt1[8192];
  const int tid = threadIdx.x;
  const int bid = blockIdx.x;
  const int ct = bid >> 6, rt = bid & 63;  // ct-major: consecutive bids share Wob slab
  const int r0 = rt * 64, c0 = ct * 128;
  const int lane = tid & 63, wave = tid >> 6;
  const int mr = (wave >> 1) * 32, nc = (wave & 1) * 64;
  const int m16 = lane & 15, quad = lane >> 4;
  const int srow = lane >> 3, sj = (lane & 7) ^ srow;
  const int mswz = (m16 & 7) << 4;

  f32x4 acc[2][4];
#pragma unroll
  for (int mt = 0; mt < 2; ++mt)
#pragma unroll
    for (int nt = 0; nt < 4; ++nt) acc[mt][nt] = (f32x4){0.f, 0.f, 0.f, 0.f};

  // stage one K-slab (64 cols) of A (64 rows) + B (128 rows): 6 glds16/wave
  auto stageK = [&](short* atb, short* btb, int kc) {
#pragma unroll
    for (int t = 0; t < 2; ++t) {
      const int crow = wave * 16 + t * 8;
      glds16(Ob + (r0 + crow + srow) * 1024 + kc * 64 + sj * 8, atb + crow * 64, lane);
    }
#pragma unroll
    for (int t = 0; t < 4; ++t) {
      const int crow = wave * 32 + t * 8;
      glds16(Wob + (c0 + crow + srow) * 1024 + kc * 64 + sj * 8, btb + crow * 64, lane);
    }
  };

  auto computeK = [&](const short* atp, const short* btp) {
    const char* atB = (const char*)atp;
    const char* btB = (const char*)btp;
#pragma unroll
    for (int kh = 0; kh < 2; ++kh) {
      short8 af[2], bf[4];
#pragma unroll
      for (int i = 0; i < 2; ++i)
        af[i] = *(const short8*)(atB + (mr + i * 16 + m16) * 128 +
                                 ((kh * 64 + quad * 16) ^ mswz));
#pragma unroll
      for (int j = 0; j < 4; ++j)
        bf[j] = *(const short8*)(btB + (nc + j * 16 + m16) * 128 +
                                 ((kh * 64 + quad * 16) ^ mswz));
      __builtin_amdgcn_s_setprio(1);
#pragma unroll
      for (int mt = 0; mt < 2; ++mt)
#pragma unroll
        for (int nt = 0; nt < 4; ++nt)
          acc[mt][nt] = __builtin_amdgcn_mfma_f32_16x16x32_bf16(af[mt], bf[nt],
                                                                acc[mt][nt], 0, 0, 0);
      __builtin_amdgcn_s_setprio(0);
    }
  };

  stageK(at0, bt0, 0);
  stageK(at1, bt1, 1);
  for (int kc = 0; kc < 14; ++kc) {
    short* atb = (kc & 1) ? at1 : at0;
    short* btb = (kc & 1) ? bt1 : bt0;
    asm volatile("s_waitcnt vmcnt(6)" ::: "memory");  // drain S(kc), keep S(kc+1)
    __builtin_amdgcn_s_barrier();
    computeK(atb, btb);
    __builtin_amdgcn_s_barrier();  // done reading this buffer
    stageK(atb, btb, kc + 2);
  }
  // peel kc=14, 15: in flight [S14(6), S15(6)]
  asm volatile("s_waitcnt vmcnt(6)" ::: "memory");
  __builtin_amdgcn_s_barrier();
  computeK(at0, bt0);
  asm volatile("s_waitcnt vmcnt(0)" ::: "memory");
  __builtin_amdgcn_s_barrier();
  computeK(at1, bt1);

#pragma unroll
  for (int nt = 0; nt < 4; ++nt) {
    const int col = c0 + nc + nt * 16 + m16;
    const float bias = bo[col];
#pragma unroll
    for (int mt = 0; mt < 2; ++mt)
#pragma unroll
      for (int rr2 = 0; rr2 < 4; ++rr2)
        out[(r0 + mr + mt * 16 + quad * 4 + rr2) * 1024 + col] = acc[mt][nt][rr2] + bias;
  }
}

// ---------------- launch ----------------
extern "C" void kernel_launch(void* const* d_in, const int* in_sizes, int n_in,
                              void* d_out, int out_size, void* d_ws, size_t ws_size,
                              hipStream_t stream) {
  const float* query = (const float*)d_in[0];
  const float* key = (const float*)d_in[1];
  const float* value = (const float*)d_in[2];
  const int* mask = (const int*)d_in[3];
  const float* Wq = (const float*)d_in[4];
  const float* Wk = (const float*)d_in[5];
  const float* Wv = (const float*)d_in[6];
  const float* Wo = (const float*)d_in[7];
  const float* bo = (const float*)d_in[8];
  float* out = (float*)d_out;

  char* ws = (char*)d_ws;
  short* Qp = (short*)(ws);                       // 8 MB
  short* Kp = (short*)(ws + 8388608);             // 8 MB
  short* Vt = (short*)(ws + 16777216);            // 8 MB
  short* Ob = (short*)(ws + 25165824);            // 8 MB (flash output, distinct from Qp)
  short* Wob = (short*)(ws + 41943040);           // 2 MB
  unsigned* mmod = (unsigned*)(ws + 44564480);    // 1 MB

  projqkv<<<3072, 256, 0, stream>>>(query, key, value, Wq, Wk, Wv, Qp, Kp, Vt);
  maskwo<<<2048, 256, 0, stream>>>(mask, Wo, Wob, mmod);
  flash64r<<<1024, 256, 0, stream>>>(Qp, Kp, Vt, mmod, Ob);
  outproj<<<512, 256, 0, stream>>>(Ob, Wob, bo, out);
}

// Round 7
// 213.050 us; speedup vs baseline: 1.0301x; 1.0301x over previous
//
#include <hip/hip_runtime.h>

typedef __attribute__((ext_vector_type(8))) short short8;
typedef __attribute__((ext_vector_type(4))) float f32x4;
typedef __attribute__((ext_vector_type(2))) int int2v;
typedef __attribute__((ext_vector_type(4))) int int4v;

__device__ __forceinline__ short f2bf(float f) {
  unsigned u = __builtin_bit_cast(unsigned, f);
  u += 0x7fff + ((u >> 16) & 1);  // RNE
  return (short)(u >> 16);
}

__device__ __forceinline__ int pk2bf(float lo, float hi) {
#if defined(__gfx950__) && __has_builtin(__builtin_amdgcn_cvt_pk_bf16_f32)
  typedef __attribute__((ext_vector_type(2))) __bf16 bf16x2;
  bf16x2 v = __builtin_amdgcn_cvt_pk_bf16_f32(lo, hi);
  return __builtin_bit_cast(int, v);
#else
  return (int)(unsigned short)(short)f2bf(lo) | (((int)f2bf(hi)) << 16);
#endif
}

// truncating pack via v_perm_b32; bias cancels through p/l normalization
__device__ __forceinline__ int pktr(float lo, float hi) {
#if __has_builtin(__builtin_amdgcn_perm)
  return (int)__builtin_amdgcn_perm(__builtin_bit_cast(unsigned, hi),
                                    __builtin_bit_cast(unsigned, lo), 0x07060302u);
#else
  return (int)(__builtin_bit_cast(unsigned, lo) >> 16) |
         (int)(__builtin_bit_cast(unsigned, hi) & 0xffff0000u);
#endif
}

__device__ __forceinline__ short8 pack8(f32x4 a, f32x4 b) {
  int4v t;
  t.x = pk2bf(a[0], a[1]);
  t.y = pk2bf(a[2], a[3]);
  t.z = pk2bf(b[0], b[1]);
  t.w = pk2bf(b[2], b[3]);
  return __builtin_bit_cast(short8, t);
}

__device__ __forceinline__ float fand(float p, int m) {
  return __builtin_bit_cast(float, __builtin_bit_cast(int, p) & m);
}

__device__ __forceinline__ int bmask(unsigned w, int bit) {
#if __has_builtin(__builtin_amdgcn_sbfe)
  return __builtin_amdgcn_sbfe((int)w, bit, 1);  // 0 or -1
#else
  return ((int)(w << (31 - bit))) >> 31;
#endif
}

__device__ __forceinline__ float fexp2(float x) {
#if __has_builtin(__builtin_amdgcn_exp2f)
  return __builtin_amdgcn_exp2f(x);
#else
  return exp2f(x);
#endif
}

// async global->LDS, 16B per lane; LDS dest = wave-uniform base + lane*16
__device__ __forceinline__ void glds16(const short* g, short* lbase, int lane) {
#if __has_builtin(__builtin_amdgcn_global_load_lds)
  __builtin_amdgcn_global_load_lds(
      (const __attribute__((address_space(1))) unsigned int*)g,
      (__attribute__((address_space(3))) unsigned int*)lbase, 16, 0, 0);
#else
  *(short8*)(lbase + lane * 8) = *(const short8*)g;
#endif
}

// =============== prep: projections + mask table + Wo cvt (r18: re-fused) ===============
// r18: projqkv+maskwo re-fused (R5->R6 showed the split cost ~7us of launch gap).
// Mask-table bit layout for the 2x2-split flash: dword per tid=(qh,kh,quad,m16),
// bit[hb*16 + qg*8 + kg*4 + r] = mask[q = qh*32+qg*16+m16][key = (kp*2+hb)*64 +
// kh*32 + kg*16 + quad*4 + r]. V column permutation sigma' UNCHANGED from r15
// (verified: sigma'(h32*32+kg*16+qk*4+r) = qk*8+kg*4+r+h32*32 serves both layouts).
__global__ __launch_bounds__(256) void prep(const float* __restrict__ q,
                                            const float* __restrict__ k,
                                            const float* __restrict__ v,
                                            const float* __restrict__ Wq,
                                            const float* __restrict__ Wk,
                                            const float* __restrict__ Wv,
                                            const float* __restrict__ Wo,
                                            const int* __restrict__ mask,
                                            short* __restrict__ Qp,
                                            short* __restrict__ Kp,
                                            short* __restrict__ Vtp,
                                            short* __restrict__ Wob,
                                            unsigned* __restrict__ mmod) {
  const int bid = blockIdx.x;
  const int tid = threadIdx.x;

  if (bid >= 4096) {  // ---- Wo convert (1024 blocks) ----
    const int i = ((bid - 4096) * 256 + tid) * 4;
    const f32x4 x = *(const f32x4*)&Wo[i];
    int2v o;
    o.x = pk2bf(x[0], x[1]);
    o.y = pk2bf(x[2], x[3]);
    *(int2v*)&Wob[i] = o;
    return;
  }
  if (bid >= 3072) {  // ---- mask table (1024 blocks, coalesced LDS-transpose) ----
    __shared__ __attribute__((aligned(16))) unsigned char mbits[8192];  // [64][128]
    const int mb = bid - 3072;       // (b*32+q64)*16 + kp
    const int kp = mb & 15, bq = mb >> 4;
    const int b_ = bq >> 5, q64 = bq & 31;
    const int* msrc = mask + b_ * 4194304 + q64 * 64 * 2048 + kp * 128;

    // phase 1: coalesced int4 loads -> 0/1 bytes into swizzled LDS
#pragma unroll
    for (int i = 0; i < 8; ++i) {
      const int idx = tid + i * 256;      // int4 index within the 64x128 region
      const int row = idx >> 5;
      const int col = (idx * 4) & 127;    // int column (== byte column)
      const int4v x = *(const int4v*)(msrc + row * 2048 + col);
      const unsigned w = (unsigned)x.x | ((unsigned)x.y << 8) |
                         ((unsigned)x.z << 16) | ((unsigned)x.w << 24);
      *(unsigned*)(mbits + row * 128 + (col ^ ((row & 7) << 4))) = w;
    }
    __syncthreads();

    // phase 2: gather 32 bits per entry, tid' == flash (qh,kh,quad,m16) mapping
    const int qh_ = tid >> 7, kh_ = (tid >> 6) & 1;
    const int qd = (tid >> 4) & 3, m16_ = tid & 15;
    unsigned d = 0;
#pragma unroll
    for (int hb = 0; hb < 2; ++hb)
#pragma unroll
      for (int qg = 0; qg < 2; ++qg) {
        const int row = qh_ * 32 + qg * 16 + m16_;
        const unsigned char* rb = mbits + row * 128;
        const int swz = (row & 7) << 4;
#pragma unroll
        for (int kg = 0; kg < 2; ++kg) {
          const unsigned w = *(const unsigned*)(
              rb + ((hb * 64 + kh_ * 32 + kg * 16 + qd * 4) ^ swz));
          const unsigned nib = (((w & 0x01010101u) * 0x01020408u) >> 24) & 0xFu;
          d |= nib << (hb * 16 + qg * 8 + kg * 4);
        }
      }
    mmod[mb * 256 + tid] = d;
    return;
  }

  // ---- projection: Out = X @ W^T on a 64-row slab (3072 blocks) ----
  __shared__ short xt[64][72];
  __shared__ short ot[64][72];
  const int mode = bid >> 10;
  const int bt = bid & 1023;
  const float* X;
  const float* W;
  float scale;
  if (mode == 0) { X = q; W = Wq; scale = 0.045084220f; }  // log2(e)/32 folded into Q
  else if (mode == 1) { X = k; W = Wk; scale = 1.0f; }
  else { X = v; W = Wv; scale = 1.0f; }

  const int r0 = bt * 64;
  const int row = tid >> 2, seg = (tid & 3) * 16;
  const f32x4* xs = (const f32x4*)(X + (r0 + row) * 64 + seg);
  const f32x4 x0 = xs[0], x1 = xs[1], x2 = xs[2], x3 = xs[3];
  *(short8*)&xt[row][seg] = pack8(x0, x1);
  *(short8*)&xt[row][seg + 8] = pack8(x2, x3);
  __syncthreads();

  const int lane = tid & 63, wave = tid >> 6;
  const int m16 = lane & 15, quad = lane >> 4;

  const short8 a0 = *(const short8*)&xt[wave * 16 + m16][quad * 8];
  const short8 a1 = *(const short8*)&xt[wave * 16 + m16][32 + quad * 8];

  f32x4 acc[4];
#pragma unroll
  for (int nt = 0; nt < 4; ++nt) {
    const f32x4* wp0 = (const f32x4*)&W[(nt * 16 + m16) * 64 + quad * 8];
    const f32x4* wp1 = (const f32x4*)&W[(nt * 16 + m16) * 64 + 32 + quad * 8];
    const short8 b0 = pack8(wp0[0], wp0[1]);
    const short8 b1 = pack8(wp1[0], wp1[1]);
    f32x4 z = (f32x4){0.f, 0.f, 0.f, 0.f};
    z = __builtin_amdgcn_mfma_f32_16x16x32_bf16(a0, b0, z, 0, 0, 0);
    z = __builtin_amdgcn_mfma_f32_16x16x32_bf16(a1, b1, z, 0, 0, 0);
    acc[nt] = z;
  }

  if (mode != 2) {
#pragma unroll
    for (int nt = 0; nt < 4; ++nt)
#pragma unroll
      for (int r = 0; r < 4; ++r)
        ot[wave * 16 + quad * 4 + r][nt * 16 + m16] = f2bf(acc[nt][r] * scale);
  } else {
    // transposed + sigma'-permuted: ot[d][sigma'(key)],
    // key = wave*16 + quad*4 + r -> sigma' = quad*8 + (wave&1)*4 + r + (wave>>1)*32
#pragma unroll
    for (int nt = 0; nt < 4; ++nt)
#pragma unroll
      for (int r = 0; r < 4; ++r)
        ot[nt * 16 + m16][quad * 8 + (wave & 1) * 4 + r + (wave >> 1) * 32] =
            f2bf(acc[nt][r]);
  }
  __syncthreads();

  const int orow = tid >> 2, opart = tid & 3;
  if (mode != 2) {
    short* dst = (mode == 0 ? Qp : Kp) + (r0 + orow) * 64 + opart * 16;
    *(short8*)&dst[0] = *(const short8*)&ot[orow][opart * 16];
    *(short8*)&dst[8] = *(const short8*)&ot[orow][opart * 16 + 8];
  } else {
    const int bh = r0 >> 11, s0 = r0 & 2047;
    short* dst = Vtp + bh * 131072 + orow * 2048 + s0 + opart * 16;
    *(short8*)&dst[0] = *(const short8*)&ot[orow][opart * 16];
    *(short8*)&dst[8] = *(const short8*)&ot[orow][opart * 16 + 8];
  }
}

// =============== flash64q: 64 q-rows, 2x2 wave split (q-half x key-half) ===============
// r18: LDS-read halving at constant everything-else. r17's pipe accounting: LDS reads
// were 16KB/wave/tile (~38us of LDS-pipe across the kernel) co-dominant with VALU 52%.
// Wave (qh=wave>>1, kh=wave&1) now owns 32 q x 32 keys: QK reads HALF of K (4KB),
// PV reads HALF of V (4KB) -> 8KB/wave/tile, with the SAME 18 MFMA, 16 exp, 8 pktr
// per wave per tile and the SAME 2-barrier/counted-vmcnt structure (in-reg P made the
// k-split free — r14's P round-trip is gone). K staging, V sigma' layout, XOR swizzles
// all unchanged (algebra in prep comment). Epilogue: one cross-kh O/l combine through
// the freed K/V LDS buffers (3 barriers, once per block).
// vmcnt ledger (verified): prologue aq4+M0+S0(4)+S1(4)+M1 = 14 -> vmcnt(5) drains
// aq+M0+S0; steady waitA/waitB outstanding 10/9 -> vmcnt(5)/(5); peel (4)/(0).
__global__ __launch_bounds__(256) void flash64q(const short* __restrict__ Qp,
                                                const short* __restrict__ Kp,
                                                const short* __restrict__ Vt,
                                                const unsigned* __restrict__ mmod,
                                                short* __restrict__ Ob) {
  __shared__ __attribute__((aligned(16))) short kt0[4096];
  __shared__ __attribute__((aligned(16))) short kt1[4096];
  __shared__ __attribute__((aligned(16))) short vt0[4096];
  __shared__ __attribute__((aligned(16))) short vt1[4096];
  const int tid = threadIdx.x;
  const int bid = blockIdx.x;
  const int local = bid >> 3;  // XCD-grouping on bid&7
  const int qblk = local & 31;
  const int bh = (bid & 7) * 4 + (local >> 5);
  const int q0 = qblk << 6;
  const int b = bh >> 4;
  const short* Qh = Qp + bh * 131072;
  const short* Kh = Kp + bh * 131072;
  const short* Vh = Vt + bh * 131072;
  const int lane = tid & 63, wave = tid >> 6;
  const int qh = wave >> 1, kh = wave & 1;
  const int m16 = lane & 15, quad = lane >> 4;
  const int srow = lane >> 3, sj = (lane & 7) ^ srow;
  const int mlow = m16 & 7;
  // QK A-frag (K rows kh*32+kg*16+m16, d-chunk (h*4+quad)^(m16&7); h=1 via ^64)
  const int kqoff = kh * 4096 + m16 * 128 + ((quad ^ mlow) * 16);
  // PV B-frag (V rows dt*16+m16, key-chunk (kh*4+quad)^(m16&7))
  const int pvoff = m16 * 128 + ((((kh << 2) | quad) ^ mlow) * 16);
  // per-lane mask dword: maskwo wrote exactly this tid's layout
  const unsigned* mq = mmod + ((b * 32 + qblk) * 16) * 256 + tid;

  const short onebf = (short)0x3F80;  // bf16 1.0
  const short8 ones = (short8){onebf, onebf, onebf, onebf, onebf, onebf, onebf, onebf};

  short8 aq[2][2];  // [qg][h]: Q rows qh*32+qg*16+m16
#pragma unroll
  for (int qg = 0; qg < 2; ++qg)
#pragma unroll
    for (int h = 0; h < 2; ++h)
      aq[qg][h] = *(const short8*)&Qh[(q0 + qh * 32 + qg * 16 + m16) * 64 +
                                      h * 32 + quad * 8];

  f32x4 oaccL[2];  // l partial (ones-MFMA): oaccL[qg][r] = l[q_loc=qg*16+quad*4+r]
  oaccL[0] = (f32x4){0.f, 0.f, 0.f, 0.f};
  oaccL[1] = (f32x4){0.f, 0.f, 0.f, 0.f};
  f32x4 oacc[2][4];  // O partial: [qg][dt][r] = O[q_loc=qg*16+quad*4+r][d=dt*16+m16]
#pragma unroll
  for (int qg = 0; qg < 2; ++qg)
#pragma unroll
    for (int dt = 0; dt < 4; ++dt) oacc[qg][dt] = (f32x4){0.f, 0.f, 0.f, 0.f};

  // stage 64-key tile ka into (ktb, vtb); 4 glds16 per wave (+4 vmcnt)
  auto stage = [&](short* ktb, short* vtb, int ka) {
#pragma unroll
    for (int t = 0; t < 2; ++t) {
      const int crow = wave * 16 + t * 8;
      glds16(Kh + (ka * 64 + crow + srow) * 64 + sj * 8, ktb + crow * 64, lane);
      glds16(Vh + (crow + srow) * 2048 + ka * 64 + sj * 8, vtb + crow * 64, lane);
    }
  };

  // tile: swapped QK^T (own 32 keys) -> in-reg P -> PV (own key-half of V)
  auto compute = [&](const short* ktp, const short* vtp, unsigned mw, int bb) {
    const char* ktB = (const char*)ktp;
    const char* vtB = (const char*)vtp;
    f32x4 s[2][2];  // s[qg][kg][r] = S[key=kh*32+kg*16+quad*4+r][q=qh*32+qg*16+m16]
    __builtin_amdgcn_s_setprio(1);
#pragma unroll
    for (int kg = 0; kg < 2; ++kg) {
      const short8 kb0 = *(const short8*)(ktB + kqoff + kg * 2048);
      const short8 kb1 = *(const short8*)(ktB + (kqoff ^ 64) + kg * 2048);
#pragma unroll
      for (int qg = 0; qg < 2; ++qg) {
        f32x4 z = (f32x4){0.f, 0.f, 0.f, 0.f};
        z = __builtin_amdgcn_mfma_f32_16x16x32_bf16(kb0, aq[qg][0], z, 0, 0, 0);
        z = __builtin_amdgcn_mfma_f32_16x16x32_bf16(kb1, aq[qg][1], z, 0, 0, 0);
        s[qg][kg] = z;
      }
    }
    __builtin_amdgcn_s_setprio(0);

    // p = exp2(s) & mask-bit
    float p[2][2][4];
#pragma unroll
    for (int qg = 0; qg < 2; ++qg)
#pragma unroll
      for (int kg = 0; kg < 2; ++kg)
#pragma unroll
        for (int r = 0; r < 4; ++r)
          p[qg][kg][r] =
              fand(fexp2(s[qg][kg][r]), bmask(mw, bb + qg * 8 + kg * 4 + r));

    // pack per-qg PV A-fragments: kslot quad*8 + kg*4 + r (matches sigma')
    short8 ap[2];
#pragma unroll
    for (int qg = 0; qg < 2; ++qg) {
      int4v t;
      t.x = pktr(p[qg][0][0], p[qg][0][1]);
      t.y = pktr(p[qg][0][2], p[qg][0][3]);
      t.z = pktr(p[qg][1][0], p[qg][1][1]);
      t.w = pktr(p[qg][1][2], p[qg][1][3]);
      ap[qg] = __builtin_bit_cast(short8, t);
    }

    // O += P V (key-half of V); l += P·1
    __builtin_amdgcn_s_setprio(1);
    oaccL[0] = __builtin_amdgcn_mfma_f32_16x16x32_bf16(ap[0], ones, oaccL[0], 0, 0, 0);
    oaccL[1] = __builtin_amdgcn_mfma_f32_16x16x32_bf16(ap[1], ones, oaccL[1], 0, 0, 0);
#pragma unroll
    for (int dt = 0; dt < 4; ++dt) {
      const short8 vb = *(const short8*)(vtB + pvoff + dt * 2048);
#pragma unroll
      for (int qg = 0; qg < 2; ++qg)
        oacc[qg][dt] =
            __builtin_amdgcn_mfma_f32_16x16x32_bf16(ap[qg], vb, oacc[qg][dt], 0, 0, 0);
    }
    __builtin_amdgcn_s_setprio(0);
  };

  // ---- prologue ----
  unsigned mw = mq[0];
  stage(kt0, vt0, 0);
  stage(kt1, vt1, 1);

  for (int kk = 0; kk < 15; ++kk) {
    const unsigned mwn = mq[(kk + 1) * 256];
    asm volatile("s_waitcnt vmcnt(5)" ::: "memory");
    __builtin_amdgcn_s_barrier();
    compute(kt0, vt0, mw, 0);
    __builtin_amdgcn_s_barrier();  // done reading buf0
    stage(kt0, vt0, 2 * kk + 2);
    asm volatile("s_waitcnt vmcnt(5)" ::: "memory");
    __builtin_amdgcn_s_barrier();
    compute(kt1, vt1, mw, 16);
    __builtin_amdgcn_s_barrier();  // done reading buf1
    stage(kt1, vt1, 2 * kk + 3);
    mw = mwn;
  }
  // peeled kk=15: outstanding [M15(1), S30(4), S31(4)]
  asm volatile("s_waitcnt vmcnt(4)" ::: "memory");
  __builtin_amdgcn_s_barrier();
  compute(kt0, vt0, mw, 0);
  asm volatile("s_waitcnt vmcnt(0)" ::: "memory");
  __builtin_amdgcn_s_barrier();
  compute(kt1, vt1, mw, 16);
  __builtin_amdgcn_s_barrier();  // all K/V LDS reads done; repurpose buffers

  // ---- epilogue: cross-kh combine ----
  // kh=1 waves publish O/l partials; kh=0 waves combine+normalize; all store.
  char* const P0 = (char*)kt0;   // qh=0 O-partial f32 [32 q][64 d], XOR-swizzled
  char* const P1 = (char*)kt1;   // qh=1
  float* const lx = (float*)vt0; // [64] l partials from kh=1
  char* const pC = qh ? P1 : P0;

  if (kh == 1) {
#pragma unroll
    for (int qg = 0; qg < 2; ++qg)
#pragma unroll
      for (int r = 0; r < 4; ++r) {
        const int ql = qg * 16 + quad * 4 + r;
#pragma unroll
        for (int dt = 0; dt < 4; ++dt)
          *(float*)(pC + ql * 256 + (((dt * 16 + m16) * 4) ^ ((ql & 7) << 4))) =
              oacc[qg][dt][r];
        if (m16 == 0) lx[qh * 32 + ql] = oaccL[qg][r];
      }
  }
  asm volatile("s_waitcnt lgkmcnt(0)" ::: "memory");
  __builtin_amdgcn_s_barrier();

  char* const ob = (char*)vt1;  // bf16 staging [64 q][64 d], XOR-swizzled
  if (kh == 0) {
#pragma unroll
    for (int qg = 0; qg < 2; ++qg)
#pragma unroll
      for (int r = 0; r < 4; ++r) {
        const int ql = qg * 16 + quad * 4 + r;
        const float lt = oaccL[qg][r] + lx[qh * 32 + ql];
        const float inv = 1.0f / lt;
        const int qrow = qh * 32 + ql;
#pragma unroll
        for (int dt = 0; dt < 4; ++dt) {
          const float part =
              *(const float*)(pC + ql * 256 + (((dt * 16 + m16) * 4) ^ ((ql & 7) << 4)));
          *(short*)(ob + qrow * 128 + ((dt * 32 + m16 * 2) ^ ((qrow & 7) << 4))) =
              f2bf((oacc[qg][dt][r] + part) * inv);
        }
      }
  }
  asm volatile("s_waitcnt lgkmcnt(0)" ::: "memory");
  __builtin_amdgcn_s_barrier();

  // coalesced O store (16 rows per wave)
  const int orow = lane >> 2, opart = lane & 3;
  const int prow = wave * 16 + orow;
  const int oswz = (orow & 7) << 4;
  short* og = Ob + (bh * 2048 + q0 + prow) * 64 + opart * 16;
  *(short8*)&og[0] = *(const short8*)(ob + prow * 128 + ((opart * 32) ^ oswz));
  *(short8*)&og[8] = *(const short8*)(ob + prow * 128 + ((opart * 32 + 16) ^ oswz));
}

// =============== outproj: out = Ob @ Wo^T + bo, 64x128 tiles, pipelined ===============
// r16 structure (unchanged): glds16 staging, row-XOR swizzle, double-buffer,
// counted vmcnt(6), peel 6/0. LDS 48KB, 2 blocks/CU.
__global__ __launch_bounds__(256) void outproj(const short* __restrict__ Ob,
                                               const short* __restrict__ Wob,
                                               const float* __restrict__ bo,
                                               float* __restrict__ out) {
  __shared__ __attribute__((aligned(16))) short at0[4096];
  __shared__ __attribute__((aligned(16))) short at1[4096];
  __shared__ __attribute__((aligned(16))) short bt0[8192];
  __shared__ __attribute__((aligned(16))) short bt1[8192];
  const int tid = threadIdx.x;
  const int bid = blockIdx.x;
  const int ct = bid >> 6, rt = bid & 63;  // ct-major: consecutive bids share Wob slab
  const int r0 = rt * 64, c0 = ct * 128;
  const int lane = tid & 63, wave = tid >> 6;
  const int mr = (wave >> 1) * 32, nc = (wave & 1) * 64;
  const int m16 = lane & 15, quad = lane >> 4;
  const int srow = lane >> 3, sj = (lane & 7) ^ srow;
  const int mswz = (m16 & 7) << 4;

  f32x4 acc[2][4];
#pragma unroll
  for (int mt = 0; mt < 2; ++mt)
#pragma unroll
    for (int nt = 0; nt < 4; ++nt) acc[mt][nt] = (f32x4){0.f, 0.f, 0.f, 0.f};

  // stage one K-slab (64 cols) of A (64 rows) + B (128 rows): 6 glds16/wave
  auto stageK = [&](short* atb, short* btb, int kc) {
#pragma unroll
    for (int t = 0; t < 2; ++t) {
      const int crow = wave * 16 + t * 8;
      glds16(Ob + (r0 + crow + srow) * 1024 + kc * 64 + sj * 8, atb + crow * 64, lane);
    }
#pragma unroll
    for (int t = 0; t < 4; ++t) {
      const int crow = wave * 32 + t * 8;
      glds16(Wob + (c0 + crow + srow) * 1024 + kc * 64 + sj * 8, btb + crow * 64, lane);
    }
  };

  auto computeK = [&](const short* atp, const short* btp) {
    const char* atB = (const char*)atp;
    const char* btB = (const char*)btp;
#pragma unroll
    for (int kh = 0; kh < 2; ++kh) {
      short8 af[2], bf[4];
#pragma unroll
      for (int i = 0; i < 2; ++i)
        af[i] = *(const short8*)(atB + (mr + i * 16 + m16) * 128 +
                                 ((kh * 64 + quad * 16) ^ mswz));
#pragma unroll
      for (int j = 0; j < 4; ++j)
        bf[j] = *(const short8*)(btB + (nc + j * 16 + m16) * 128 +
                                 ((kh * 64 + quad * 16) ^ mswz));
      __builtin_amdgcn_s_setprio(1);
#pragma unroll
      for (int mt = 0; mt < 2; ++mt)
#pragma unroll
        for (int nt = 0; nt < 4; ++nt)
          acc[mt][nt] = __builtin_amdgcn_mfma_f32_16x16x32_bf16(af[mt], bf[nt],
                                                                acc[mt][nt], 0, 0, 0);
      __builtin_amdgcn_s_setprio(0);
    }
  };

  stageK(at0, bt0, 0);
  stageK(at1, bt1, 1);
  for (int kc = 0; kc < 14; ++kc) {
    short* atb = (kc & 1) ? at1 : at0;
    short* btb = (kc & 1) ? bt1 : bt0;
    asm volatile("s_waitcnt vmcnt(6)" ::: "memory");  // drain S(kc), keep S(kc+1)
    __builtin_amdgcn_s_barrier();
    computeK(atb, btb);
    __builtin_amdgcn_s_barrier();  // done reading this buffer
    stageK(atb, btb, kc + 2);
  }
  // peel kc=14, 15: in flight [S14(6), S15(6)]
  asm volatile("s_waitcnt vmcnt(6)" ::: "memory");
  __builtin_amdgcn_s_barrier();
  computeK(at0, bt0);
  asm volatile("s_waitcnt vmcnt(0)" ::: "memory");
  __builtin_amdgcn_s_barrier();
  computeK(at1, bt1);

#pragma unroll
  for (int nt = 0; nt < 4; ++nt) {
    const int col = c0 + nc + nt * 16 + m16;
    const float bias = bo[col];
#pragma unroll
    for (int mt = 0; mt < 2; ++mt)
#pragma unroll
      for (int rr2 = 0; rr2 < 4; ++rr2)
        out[(r0 + mr + mt * 16 + quad * 4 + rr2) * 1024 + col] = acc[mt][nt][rr2] + bias;
  }
}

// ---------------- launch ----------------
extern "C" void kernel_launch(void* const* d_in, const int* in_sizes, int n_in,
                              void* d_out, int out_size, void* d_ws, size_t ws_size,
                              hipStream_t stream) {
  const float* query = (const float*)d_in[0];
  const float* key = (const float*)d_in[1];
  const float* value = (const float*)d_in[2];
  const int* mask = (const int*)d_in[3];
  const float* Wq = (const float*)d_in[4];
  const float* Wk = (const float*)d_in[5];
  const float* Wv = (const float*)d_in[6];
  const float* Wo = (const float*)d_in[7];
  const float* bo = (const float*)d_in[8];
  float* out = (float*)d_out;

  char* ws = (char*)d_ws;
  short* Qp = (short*)(ws);                       // 8 MB
  short* Kp = (short*)(ws + 8388608);             // 8 MB
  short* Vt = (short*)(ws + 16777216);            // 8 MB
  short* Ob = (short*)(ws + 25165824);            // 8 MB (flash output, distinct from Qp)
  short* Wob = (short*)(ws + 41943040);           // 2 MB
  unsigned* mmod = (unsigned*)(ws + 44564480);    // 1 MB

  prep<<<5120, 256, 0, stream>>>(query, key, value, Wq, Wk, Wv, Wo, mask,
                                 Qp, Kp, Vt, Wob, mmod);
  flash64q<<<1024, 256, 0, stream>>>(Qp, Kp, Vt, mmod, Ob);
  outproj<<<512, 256, 0, stream>>>(Ob, Wob, bo, out);
}

// Round 8
// 210.092 us; speedup vs baseline: 1.0446x; 1.0141x over previous
//
#include <hip/hip_runtime.h>

typedef __attribute__((ext_vector_type(8))) short short8;
typedef __attribute__((ext_vector_type(4))) float f32x4;
typedef __attribute__((ext_vector_type(2))) int int2v;
typedef __attribute__((ext_vector_type(4))) int int4v;

__device__ __forceinline__ short f2bf(float f) {
  unsigned u = __builtin_bit_cast(unsigned, f);
  u += 0x7fff + ((u >> 16) & 1);  // RNE
  return (short)(u >> 16);
}

__device__ __forceinline__ int pk2bf(float lo, float hi) {
#if defined(__gfx950__) && __has_builtin(__builtin_amdgcn_cvt_pk_bf16_f32)
  typedef __attribute__((ext_vector_type(2))) __bf16 bf16x2;
  bf16x2 v = __builtin_amdgcn_cvt_pk_bf16_f32(lo, hi);
  return __builtin_bit_cast(int, v);
#else
  return (int)(unsigned short)(short)f2bf(lo) | (((int)f2bf(hi)) << 16);
#endif
}

// truncating pack via v_perm_b32; bias cancels through p/l normalization
__device__ __forceinline__ int pktr(float lo, float hi) {
#if __has_builtin(__builtin_amdgcn_perm)
  return (int)__builtin_amdgcn_perm(__builtin_bit_cast(unsigned, hi),
                                    __builtin_bit_cast(unsigned, lo), 0x07060302u);
#else
  return (int)(__builtin_bit_cast(unsigned, lo) >> 16) |
         (int)(__builtin_bit_cast(unsigned, hi) & 0xffff0000u);
#endif
}

__device__ __forceinline__ short8 pack8(f32x4 a, f32x4 b) {
  int4v t;
  t.x = pk2bf(a[0], a[1]);
  t.y = pk2bf(a[2], a[3]);
  t.z = pk2bf(b[0], b[1]);
  t.w = pk2bf(b[2], b[3]);
  return __builtin_bit_cast(short8, t);
}

__device__ __forceinline__ float fand(float p, int m) {
  return __builtin_bit_cast(float, __builtin_bit_cast(int, p) & m);
}

__device__ __forceinline__ int bmask(unsigned w, int bit) {
#if __has_builtin(__builtin_amdgcn_sbfe)
  return __builtin_amdgcn_sbfe((int)w, bit, 1);  // 0 or -1
#else
  return ((int)(w << (31 - bit))) >> 31;
#endif
}

__device__ __forceinline__ float fexp2(float x) {
#if __has_builtin(__builtin_amdgcn_exp2f)
  return __builtin_amdgcn_exp2f(x);
#else
  return exp2f(x);
#endif
}

// async global->LDS, 16B per lane; LDS dest = wave-uniform base + lane*16
__device__ __forceinline__ void glds16(const short* g, short* lbase, int lane) {
#if __has_builtin(__builtin_amdgcn_global_load_lds)
  __builtin_amdgcn_global_load_lds(
      (const __attribute__((address_space(1))) unsigned int*)g,
      (__attribute__((address_space(3))) unsigned int*)lbase, 16, 0, 0);
#else
  *(short8*)(lbase + lane * 8) = *(const short8*)g;
#endif
}

// =============== prep: projections + mask table + Wo cvt (single launch) ===============
// r19: RECOMBINATION. r18's fused prep (non-flash 161->136 us, proven) but with the
// r17 mask bit layout restored (flash reverts to flash64r which reads that layout):
// dword per tid'=(wv,qd,m16), bit[hb*16+grp*4+r] = mask[q=wv*16+m16]
// [key=(kp*2+hb)*64 + grp*16 + qd*4 + r]. V sigma' unchanged:
// sigma'(grp*16+qk*4+r) = qk*8 + (grp&1)*4 + r + (grp>>1)*32.
// k-split lesson (r14: 76.6, r18: 77.1 vs r17 q-split 58.4): wave-owns-full-K q-split
// is the proven-fastest flash structure; k-splits add ~17us unexplained stall. Reverted.
__global__ __launch_bounds__(256) void prep(const float* __restrict__ q,
                                            const float* __restrict__ k,
                                            const float* __restrict__ v,
                                            const float* __restrict__ Wq,
                                            const float* __restrict__ Wk,
                                            const float* __restrict__ Wv,
                                            const float* __restrict__ Wo,
                                            const int* __restrict__ mask,
                                            short* __restrict__ Qp,
                                            short* __restrict__ Kp,
                                            short* __restrict__ Vtp,
                                            short* __restrict__ Wob,
                                            unsigned* __restrict__ mmod) {
  const int bid = blockIdx.x;
  const int tid = threadIdx.x;

  if (bid >= 4096) {  // ---- Wo convert (1024 blocks) ----
    const int i = ((bid - 4096) * 256 + tid) * 4;
    const f32x4 x = *(const f32x4*)&Wo[i];
    int2v o;
    o.x = pk2bf(x[0], x[1]);
    o.y = pk2bf(x[2], x[3]);
    *(int2v*)&Wob[i] = o;
    return;
  }
  if (bid >= 3072) {  // ---- mask table (1024 blocks, coalesced LDS-transpose) ----
    __shared__ __attribute__((aligned(16))) unsigned char mbits[8192];  // [64][128]
    const int mb = bid - 3072;       // (b*32+q64)*16 + kp
    const int kp = mb & 15, bq = mb >> 4;
    const int b_ = bq >> 5, q64 = bq & 31;
    const int* msrc = mask + b_ * 4194304 + q64 * 64 * 2048 + kp * 128;

    // phase 1: coalesced int4 loads -> 0/1 bytes into swizzled LDS
#pragma unroll
    for (int i = 0; i < 8; ++i) {
      const int idx = tid + i * 256;      // int4 index within the 64x128 region
      const int row = idx >> 5;
      const int col = (idx * 4) & 127;    // int column (== byte column)
      const int4v x = *(const int4v*)(msrc + row * 2048 + col);
      const unsigned w = (unsigned)x.x | ((unsigned)x.y << 8) |
                         ((unsigned)x.z << 16) | ((unsigned)x.w << 24);
      *(unsigned*)(mbits + row * 128 + (col ^ ((row & 7) << 4))) = w;
    }
    __syncthreads();

    // phase 2: gather 32 bits per entry (r17 layout; tid' == flash64r lane mapping)
    const int wv = tid >> 6, qd = (tid >> 4) & 3, m16_ = tid & 15;
    const int row = wv * 16 + m16_;
    const int swz = (row & 7) << 4;
    const unsigned char* rb = mbits + row * 128;
    unsigned d = 0;
#pragma unroll
    for (int hb = 0; hb < 2; ++hb)
#pragma unroll
      for (int grp = 0; grp < 4; ++grp) {
        const unsigned w =
            *(const unsigned*)(rb + ((hb * 64 + grp * 16 + qd * 4) ^ swz));
        const unsigned nib = (((w & 0x01010101u) * 0x01020408u) >> 24) & 0xFu;
        d |= nib << (hb * 16 + grp * 4);
      }
    mmod[mb * 256 + tid] = d;
    return;
  }

  // ---- projection: Out = X @ W^T on a 64-row slab (3072 blocks) ----
  __shared__ short xt[64][72];
  __shared__ short ot[64][72];
  const int mode = bid >> 10;
  const int bt = bid & 1023;
  const float* X;
  const float* W;
  float scale;
  if (mode == 0) { X = q; W = Wq; scale = 0.045084220f; }  // log2(e)/32 folded into Q
  else if (mode == 1) { X = k; W = Wk; scale = 1.0f; }
  else { X = v; W = Wv; scale = 1.0f; }

  const int r0 = bt * 64;
  const int row = tid >> 2, seg = (tid & 3) * 16;
  const f32x4* xs = (const f32x4*)(X + (r0 + row) * 64 + seg);
  const f32x4 x0 = xs[0], x1 = xs[1], x2 = xs[2], x3 = xs[3];
  *(short8*)&xt[row][seg] = pack8(x0, x1);
  *(short8*)&xt[row][seg + 8] = pack8(x2, x3);
  __syncthreads();

  const int lane = tid & 63, wave = tid >> 6;
  const int m16 = lane & 15, quad = lane >> 4;

  const short8 a0 = *(const short8*)&xt[wave * 16 + m16][quad * 8];
  const short8 a1 = *(const short8*)&xt[wave * 16 + m16][32 + quad * 8];

  f32x4 acc[4];
#pragma unroll
  for (int nt = 0; nt < 4; ++nt) {
    const f32x4* wp0 = (const f32x4*)&W[(nt * 16 + m16) * 64 + quad * 8];
    const f32x4* wp1 = (const f32x4*)&W[(nt * 16 + m16) * 64 + 32 + quad * 8];
    const short8 b0 = pack8(wp0[0], wp0[1]);
    const short8 b1 = pack8(wp1[0], wp1[1]);
    f32x4 z = (f32x4){0.f, 0.f, 0.f, 0.f};
    z = __builtin_amdgcn_mfma_f32_16x16x32_bf16(a0, b0, z, 0, 0, 0);
    z = __builtin_amdgcn_mfma_f32_16x16x32_bf16(a1, b1, z, 0, 0, 0);
    acc[nt] = z;
  }

  if (mode != 2) {
#pragma unroll
    for (int nt = 0; nt < 4; ++nt)
#pragma unroll
      for (int r = 0; r < 4; ++r)
        ot[wave * 16 + quad * 4 + r][nt * 16 + m16] = f2bf(acc[nt][r] * scale);
  } else {
    // transposed + sigma'-permuted: ot[d][sigma'(key)],
    // key = wave*16 + quad*4 + r -> sigma' = quad*8 + (wave&1)*4 + r + (wave>>1)*32
#pragma unroll
    for (int nt = 0; nt < 4; ++nt)
#pragma unroll
      for (int r = 0; r < 4; ++r)
        ot[nt * 16 + m16][quad * 8 + (wave & 1) * 4 + r + (wave >> 1) * 32] =
            f2bf(acc[nt][r]);
  }
  __syncthreads();

  const int orow = tid >> 2, opart = tid & 3;
  if (mode != 2) {
    short* dst = (mode == 0 ? Qp : Kp) + (r0 + orow) * 64 + opart * 16;
    *(short8*)&dst[0] = *(const short8*)&ot[orow][opart * 16];
    *(short8*)&dst[8] = *(const short8*)&ot[orow][opart * 16 + 8];
  } else {
    const int bh = r0 >> 11, s0 = r0 & 2047;
    short* dst = Vtp + bh * 131072 + orow * 2048 + s0 + opart * 16;
    *(short8*)&dst[0] = *(const short8*)&ot[orow][opart * 16];
    *(short8*)&dst[8] = *(const short8*)&ot[orow][opart * 16 + 8];
  }
}

// =============== flash64r: 64 q-rows, in-register P, l via ones-MFMA ===============
// r19: reverted to the r17 version verbatim (58.4 us measured, MfmaUtil 26,
// VALUBusy 52, VGPR 60). Swapped-QK in-reg P, wave owns 16 q-rows x full K,
// pktr via v_perm, hoisted koff/koffx, 2 barriers/tile, counted vmcnt(5)/(5),
// peel (4)/(0), 32KB LDS, epilogue via kt0.
__global__ __launch_bounds__(256) void flash64r(const short* __restrict__ Qp,
                                                const short* __restrict__ Kp,
                                                const short* __restrict__ Vt,
                                                const unsigned* __restrict__ mmod,
                                                short* __restrict__ Ob) {
  __shared__ __attribute__((aligned(16))) short kt0[4096];
  __shared__ __attribute__((aligned(16))) short kt1[4096];
  __shared__ __attribute__((aligned(16))) short vt0[4096];
  __shared__ __attribute__((aligned(16))) short vt1[4096];
  const int tid = threadIdx.x;
  const int bid = blockIdx.x;
  const int local = bid >> 3;  // XCD-grouping on bid&7
  const int qblk = local & 31;
  const int bh = (bid & 7) * 4 + (local >> 5);
  const int q0 = qblk << 6;
  const int b = bh >> 4;
  const short* Qh = Qp + bh * 131072;
  const short* Kh = Kp + bh * 131072;
  const short* Vh = Vt + bh * 131072;
  const int lane = tid & 63, wave = tid >> 6;
  const int m16 = lane & 15, quad = lane >> 4;
  const int srow = lane >> 3, sj = (lane & 7) ^ srow;
  const int koff = m16 * 128 + ((quad ^ (m16 & 7)) * 16);
  const int koffx = koff ^ 64;
  // per-lane mask dword: table tid' = wave*64 + lane; one dword per kp (2 tiles)
  const unsigned* mq = mmod + ((b * 32 + qblk) * 16) * 256 + wave * 64 + quad * 16 + m16;

  const short onebf = (short)0x3F80;  // bf16 1.0
  const short8 ones = (short8){onebf, onebf, onebf, onebf, onebf, onebf, onebf, onebf};

  short8 aq[2];
#pragma unroll
  for (int h = 0; h < 2; ++h)
    aq[h] = *(const short8*)&Qh[(q0 + wave * 16 + m16) * 64 + h * 32 + quad * 8];

  f32x4 oaccL = (f32x4){0.f, 0.f, 0.f, 0.f};  // row-sum accumulator (l)
  f32x4 oacc[4];
#pragma unroll
  for (int dt = 0; dt < 4; ++dt) oacc[dt] = (f32x4){0.f, 0.f, 0.f, 0.f};

  // stage 64-key tile ka into (ktb, vtb); 4 glds16 per wave (+4 vmcnt)
  auto stage = [&](short* ktb, short* vtb, int ka) {
#pragma unroll
    for (int t = 0; t < 2; ++t) {
      const int crow = wave * 16 + t * 8;
      glds16(Kh + (ka * 64 + crow + srow) * 64 + sj * 8, ktb + crow * 64, lane);
      glds16(Vh + (crow + srow) * 2048 + ka * 64 + sj * 8, vtb + crow * 64, lane);
    }
  };

  // full tile: swapped QK^T -> in-register P -> PV (+ l via ones-MFMA). No LDS writes.
  auto compute = [&](const short* ktp, const short* vtp, unsigned mw, int bb) {
    const char* kb_lo = (const char*)ktp + koff;
    const char* kb_hi = (const char*)ktp + koffx;
    const char* vb_lo = (const char*)vtp + koff;
    const char* vb_hi = (const char*)vtp + koffx;
    // S^T quadrants: s[grp][r] = S[q = m16][key = grp*16 + quad*4 + r]
    f32x4 s[4];
    __builtin_amdgcn_s_setprio(1);
#pragma unroll
    for (int grp = 0; grp < 4; ++grp) {
      const short8 kb0 = *(const short8*)(kb_lo + grp * 2048);
      const short8 kb1 = *(const short8*)(kb_hi + grp * 2048);
      f32x4 z = (f32x4){0.f, 0.f, 0.f, 0.f};
      z = __builtin_amdgcn_mfma_f32_16x16x32_bf16(kb0, aq[0], z, 0, 0, 0);
      z = __builtin_amdgcn_mfma_f32_16x16x32_bf16(kb1, aq[1], z, 0, 0, 0);
      s[grp] = z;
    }
    __builtin_amdgcn_s_setprio(0);

    // p = exp2(s) & mask-bit (all 16 p's belong to q = m16)
    float p[4][4];
#pragma unroll
    for (int grp = 0; grp < 4; ++grp)
#pragma unroll
      for (int r = 0; r < 4; ++r)
        p[grp][r] = fand(fexp2(s[grp][r]), bmask(mw, bb + grp * 4 + r));

    // pack P into the PV A-fragments directly (sigma' makes these the lane's slots)
    int4v t0, t1;
    t0.x = pktr(p[0][0], p[0][1]);
    t0.y = pktr(p[0][2], p[0][3]);
    t0.z = pktr(p[1][0], p[1][1]);
    t0.w = pktr(p[1][2], p[1][3]);
    t1.x = pktr(p[2][0], p[2][1]);
    t1.y = pktr(p[2][2], p[2][3]);
    t1.z = pktr(p[3][0], p[3][1]);
    t1.w = pktr(p[3][2], p[3][3]);
    const short8 ap0 = __builtin_bit_cast(short8, t0);
    const short8 ap1 = __builtin_bit_cast(short8, t1);

    // O += P V; l += P·1 (matrix pipe; no LDS dep -> issues while vb reads land)
    __builtin_amdgcn_s_setprio(1);
    oaccL = __builtin_amdgcn_mfma_f32_16x16x32_bf16(ap0, ones, oaccL, 0, 0, 0);
    oaccL = __builtin_amdgcn_mfma_f32_16x16x32_bf16(ap1, ones, oaccL, 0, 0, 0);
#pragma unroll
    for (int dt = 0; dt < 4; ++dt) {
      const short8 vb0 = *(const short8*)(vb_lo + dt * 2048);
      const short8 vb1 = *(const short8*)(vb_hi + dt * 2048);
      f32x4 z = oacc[dt];
      z = __builtin_amdgcn_mfma_f32_16x16x32_bf16(ap0, vb0, z, 0, 0, 0);
      z = __builtin_amdgcn_mfma_f32_16x16x32_bf16(ap1, vb1, z, 0, 0, 0);
      oacc[dt] = z;
    }
    __builtin_amdgcn_s_setprio(0);
  };

  // ---- prologue: mask for kp=0, both stages; first waitA covers aq+M0+S0 ----
  unsigned mw = mq[0];
  stage(kt0, vt0, 0);
  stage(kt1, vt1, 1);

  for (int kk = 0; kk < 15; ++kk) {
    const unsigned mwn = mq[(kk + 1) * 256];
    // tile A = 2kk (buf0): drain M(kk)+S(2kk); newer = S(2kk+1)[4] + M(kk+1)[1]
    asm volatile("s_waitcnt vmcnt(5)" ::: "memory");
    __builtin_amdgcn_s_barrier();
    compute(kt0, vt0, mw, 0);
    __builtin_amdgcn_s_barrier();  // done reading buf0
    stage(kt0, vt0, 2 * kk + 2);
    // tile B = 2kk+1 (buf1): drain S(2kk+1); newer = M(kk+1)[1] + S(2kk+2)[4]
    asm volatile("s_waitcnt vmcnt(5)" ::: "memory");
    __builtin_amdgcn_s_barrier();
    compute(kt1, vt1, mw, 16);
    __builtin_amdgcn_s_barrier();  // done reading buf1
    stage(kt1, vt1, 2 * kk + 3);
    mw = mwn;
  }
  // peeled kk=15: outstanding [M15(1), S30(4), S31(4)]
  asm volatile("s_waitcnt vmcnt(4)" ::: "memory");
  __builtin_amdgcn_s_barrier();
  compute(kt0, vt0, mw, 0);
  asm volatile("s_waitcnt vmcnt(0)" ::: "memory");
  __builtin_amdgcn_s_barrier();
  compute(kt1, vt1, mw, 16);

  // ---- epilogue ----
  // l[q = quad*4 + r] = oaccL[r] on every lane (ones-B makes all 16 cols equal)
  float linv[4];
#pragma unroll
  for (int r = 0; r < 4; ++r) linv[r] = 1.0f / oaccL[r];

  // normalize, write O (bf16) into kt0 (swizzled; wave-private rows — safe: all
  // cross-wave kt0 reads finished before the barrier preceding compute(kt1))
  char* const ptB = (char*)kt0;
#pragma unroll
  for (int r = 0; r < 4; ++r) {
    const int row = wave * 16 + quad * 4 + r;
#pragma unroll
    for (int dt = 0; dt < 4; ++dt)
      *(short*)(ptB + row * 128 + ((dt * 32 + m16 * 2) ^ ((row & 7) << 4))) =
          f2bf(oacc[dt][r] * linv[r]);
  }
  asm volatile("s_waitcnt lgkmcnt(0)" ::: "memory");  // same-wave rows: no barrier

  // coalesced O store (rows partitioned within the wave)
  const int orow = lane >> 2, opart = lane & 3;
  const int prow = wave * 16 + orow;
  const int oswz = (orow & 7) << 4;
  short* og = Ob + (bh * 2048 + q0 + prow) * 64 + opart * 16;
  *(short8*)&og[0] = *(const short8*)(ptB + prow * 128 + ((opart * 32) ^ oswz));
  *(short8*)&og[8] = *(const short8*)(ptB + prow * 128 + ((opart * 32 + 16) ^ oswz));
}

// =============== outproj: out = Ob @ Wo^T + bo, 64x128 tiles, pipelined ===============
// r16 structure (unchanged): glds16 staging, row-XOR swizzle, double-buffer,
// counted vmcnt(6), peel 6/0. LDS 48KB, 2 blocks/CU.
__global__ __launch_bounds__(256) void outproj(const short* __restrict__ Ob,
                                               const short* __restrict__ Wob,
                                               const float* __restrict__ bo,
                                               float* __restrict__ out) {
  __shared__ __attribute__((aligned(16))) short at0[4096];
  __shared__ __attribute__((aligned(16))) short at1[4096];
  __shared__ __attribute__((aligned(16))) short bt0[8192];
  __shared__ __attribute__((aligned(16))) short bt1[8192];
  const int tid = threadIdx.x;
  const int bid = blockIdx.x;
  const int ct = bid >> 6, rt = bid & 63;  // ct-major: consecutive bids share Wob slab
  const int r0 = rt * 64, c0 = ct * 128;
  const int lane = tid & 63, wave = tid >> 6;
  const int mr = (wave >> 1) * 32, nc = (wave & 1) * 64;
  const int m16 = lane & 15, quad = lane >> 4;
  const int srow = lane >> 3, sj = (lane & 7) ^ srow;
  const int mswz = (m16 & 7) << 4;

  f32x4 acc[2][4];
#pragma unroll
  for (int mt = 0; mt < 2; ++mt)
#pragma unroll
    for (int nt = 0; nt < 4; ++nt) acc[mt][nt] = (f32x4){0.f, 0.f, 0.f, 0.f};

  // stage one K-slab (64 cols) of A (64 rows) + B (128 rows): 6 glds16/wave
  auto stageK = [&](short* atb, short* btb, int kc) {
#pragma unroll
    for (int t = 0; t < 2; ++t) {
      const int crow = wave * 16 + t * 8;
      glds16(Ob + (r0 + crow + srow) * 1024 + kc * 64 + sj * 8, atb + crow * 64, lane);
    }
#pragma unroll
    for (int t = 0; t < 4; ++t) {
      const int crow = wave * 32 + t * 8;
      glds16(Wob + (c0 + crow + srow) * 1024 + kc * 64 + sj * 8, btb + crow * 64, lane);
    }
  };

  auto computeK = [&](const short* atp, const short* btp) {
    const char* atB = (const char*)atp;
    const char* btB = (const char*)btp;
#pragma unroll
    for (int kh = 0; kh < 2; ++kh) {
      short8 af[2], bf[4];
#pragma unroll
      for (int i = 0; i < 2; ++i)
        af[i] = *(const short8*)(atB + (mr + i * 16 + m16) * 128 +
                                 ((kh * 64 + quad * 16) ^ mswz));
#pragma unroll
      for (int j = 0; j < 4; ++j)
        bf[j] = *(const short8*)(btB + (nc + j * 16 + m16) * 128 +
                                 ((kh * 64 + quad * 16) ^ mswz));
      __builtin_amdgcn_s_setprio(1);
#pragma unroll
      for (int mt = 0; mt < 2; ++mt)
#pragma unroll
        for (int nt = 0; nt < 4; ++nt)
          acc[mt][nt] = __builtin_amdgcn_mfma_f32_16x16x32_bf16(af[mt], bf[nt],
                                                                acc[mt][nt], 0, 0, 0);
      __builtin_amdgcn_s_setprio(0);
    }
  };

  stageK(at0, bt0, 0);
  stageK(at1, bt1, 1);
  for (int kc = 0; kc < 14; ++kc) {
    short* atb = (kc & 1) ? at1 : at0;
    short* btb = (kc & 1) ? bt1 : bt0;
    asm volatile("s_waitcnt vmcnt(6)" ::: "memory");  // drain S(kc), keep S(kc+1)
    __builtin_amdgcn_s_barrier();
    computeK(atb, btb);
    __builtin_amdgcn_s_barrier();  // done reading this buffer
    stageK(atb, btb, kc + 2);
  }
  // peel kc=14, 15: in flight [S14(6), S15(6)]
  asm volatile("s_waitcnt vmcnt(6)" ::: "memory");
  __builtin_amdgcn_s_barrier();
  computeK(at0, bt0);
  asm volatile("s_waitcnt vmcnt(0)" ::: "memory");
  __builtin_amdgcn_s_barrier();
  computeK(at1, bt1);

#pragma unroll
  for (int nt = 0; nt < 4; ++nt) {
    const int col = c0 + nc + nt * 16 + m16;
    const float bias = bo[col];
#pragma unroll
    for (int mt = 0; mt < 2; ++mt)
#pragma unroll
      for (int rr2 = 0; rr2 < 4; ++rr2)
        out[(r0 + mr + mt * 16 + quad * 4 + rr2) * 1024 + col] = acc[mt][nt][rr2] + bias;
  }
}

// ---------------- launch ----------------
extern "C" void kernel_launch(void* const* d_in, const int* in_sizes, int n_in,
                              void* d_out, int out_size, void* d_ws, size_t ws_size,
                              hipStream_t stream) {
  const float* query = (const float*)d_in[0];
  const float* key = (const float*)d_in[1];
  const float* value = (const float*)d_in[2];
  const int* mask = (const int*)d_in[3];
  const float* Wq = (const float*)d_in[4];
  const float* Wk = (const float*)d_in[5];
  const float* Wv = (const float*)d_in[6];
  const float* Wo = (const float*)d_in[7];
  const float* bo = (const float*)d_in[8];
  float* out = (float*)d_out;

  char* ws = (char*)d_ws;
  short* Qp = (short*)(ws);                       // 8 MB
  short* Kp = (short*)(ws + 8388608);             // 8 MB
  short* Vt = (short*)(ws + 16777216);            // 8 MB
  short* Ob = (short*)(ws + 25165824);            // 8 MB (flash output, distinct from Qp)
  short* Wob = (short*)(ws + 41943040);           // 2 MB
  unsigned* mmod = (unsigned*)(ws + 44564480);    // 1 MB

  prep<<<5120, 256, 0, stream>>>(query, key, value, Wq, Wk, Wv, Wo, mask,
                                 Qp, Kp, Vt, Wob, mmod);
  flash64r<<<1024, 256, 0, stream>>>(Qp, Kp, Vt, mmod, Ob);
  outproj<<<512, 256, 0, stream>>>(Ob, Wob, bo, out);
}

// Round 9
// 207.126 us; speedup vs baseline: 1.0596x; 1.0143x over previous
//
#include <hip/hip_runtime.h>

typedef __attribute__((ext_vector_type(8))) short short8;
typedef __attribute__((ext_vector_type(4))) float f32x4;
typedef __attribute__((ext_vector_type(2))) int int2v;
typedef __attribute__((ext_vector_type(4))) int int4v;

__device__ __forceinline__ short f2bf(float f) {
  unsigned u = __builtin_bit_cast(unsigned, f);
  u += 0x7fff + ((u >> 16) & 1);  // RNE
  return (short)(u >> 16);
}

__device__ __forceinline__ int pk2bf(float lo, float hi) {
#if defined(__gfx950__) && __has_builtin(__builtin_amdgcn_cvt_pk_bf16_f32)
  typedef __attribute__((ext_vector_type(2))) __bf16 bf16x2;
  bf16x2 v = __builtin_amdgcn_cvt_pk_bf16_f32(lo, hi);
  return __builtin_bit_cast(int, v);
#else
  return (int)(unsigned short)(short)f2bf(lo) | (((int)f2bf(hi)) << 16);
#endif
}

// truncating pack via v_perm_b32; bias cancels through p/l normalization
__device__ __forceinline__ int pktr(float lo, float hi) {
#if __has_builtin(__builtin_amdgcn_perm)
  return (int)__builtin_amdgcn_perm(__builtin_bit_cast(unsigned, hi),
                                    __builtin_bit_cast(unsigned, lo), 0x07060302u);
#else
  return (int)(__builtin_bit_cast(unsigned, lo) >> 16) |
         (int)(__builtin_bit_cast(unsigned, hi) & 0xffff0000u);
#endif
}

__device__ __forceinline__ short8 pack8(f32x4 a, f32x4 b) {
  int4v t;
  t.x = pk2bf(a[0], a[1]);
  t.y = pk2bf(a[2], a[3]);
  t.z = pk2bf(b[0], b[1]);
  t.w = pk2bf(b[2], b[3]);
  return __builtin_bit_cast(short8, t);
}

__device__ __forceinline__ float fand(float p, int m) {
  return __builtin_bit_cast(float, __builtin_bit_cast(int, p) & m);
}

__device__ __forceinline__ int bmask(unsigned w, int bit) {
#if __has_builtin(__builtin_amdgcn_sbfe)
  return __builtin_amdgcn_sbfe((int)w, bit, 1);  // 0 or -1
#else
  return ((int)(w << (31 - bit))) >> 31;
#endif
}

__device__ __forceinline__ float fexp2(float x) {
#if __has_builtin(__builtin_amdgcn_exp2f)
  return __builtin_amdgcn_exp2f(x);
#else
  return exp2f(x);
#endif
}

// async global->LDS, 16B per lane; LDS dest = wave-uniform base + lane*16
__device__ __forceinline__ void glds16(const short* g, short* lbase, int lane) {
#if __has_builtin(__builtin_amdgcn_global_load_lds)
  __builtin_amdgcn_global_load_lds(
      (const __attribute__((address_space(1))) unsigned int*)g,
      (__attribute__((address_space(3))) unsigned int*)lbase, 16, 0, 0);
#else
  *(short8*)(lbase + lane * 8) = *(const short8*)g;
#endif
}

// =============== prep: projections + mask table + Wo cvt (r20: fewer, fatter blocks) ===============
// r20: grid 5120 -> 2816. Projections: 512 blocks/mode x 2 slabs each, W-fragment
// pack hoisted out of the slab loop (done once, reused). xt/ot reuse across slabs is
// covered by each slab's existing 2 barriers (slab-N xt reads complete before its
// 1st barrier; slab-N ot-store LDS reads complete before slab-N+1's 1st barrier —
// compiler-emitted full waitcnt at s_barrier). Wo: 256 blocks x 16 elems/thread.
// Mask table and all layouts unchanged from r19 (proven with flash64r).
__global__ __launch_bounds__(256) void prep(const float* __restrict__ q,
                                            const float* __restrict__ k,
                                            const float* __restrict__ v,
                                            const float* __restrict__ Wq,
                                            const float* __restrict__ Wk,
                                            const float* __restrict__ Wv,
                                            const float* __restrict__ Wo,
                                            const int* __restrict__ mask,
                                            short* __restrict__ Qp,
                                            short* __restrict__ Kp,
                                            short* __restrict__ Vtp,
                                            short* __restrict__ Wob,
                                            unsigned* __restrict__ mmod) {
  const int bid = blockIdx.x;
  const int tid = threadIdx.x;

  if (bid >= 2560) {  // ---- Wo convert (256 blocks, 16 elems/thread) ----
    const int base = ((bid - 2560) * 256 + tid) * 16;
#pragma unroll
    for (int j = 0; j < 4; ++j) {
      const int i = base + j * 4;
      const f32x4 x = *(const f32x4*)&Wo[i];
      int2v o;
      o.x = pk2bf(x[0], x[1]);
      o.y = pk2bf(x[2], x[3]);
      *(int2v*)&Wob[i] = o;
    }
    return;
  }
  if (bid >= 1536) {  // ---- mask table (1024 blocks, coalesced LDS-transpose) ----
    __shared__ __attribute__((aligned(16))) unsigned char mbits[8192];  // [64][128]
    const int mb = bid - 1536;       // (b*32+q64)*16 + kp
    const int kp = mb & 15, bq = mb >> 4;
    const int b_ = bq >> 5, q64 = bq & 31;
    const int* msrc = mask + b_ * 4194304 + q64 * 64 * 2048 + kp * 128;

    // phase 1: coalesced int4 loads -> 0/1 bytes into swizzled LDS
#pragma unroll
    for (int i = 0; i < 8; ++i) {
      const int idx = tid + i * 256;      // int4 index within the 64x128 region
      const int row = idx >> 5;
      const int col = (idx * 4) & 127;    // int column (== byte column)
      const int4v x = *(const int4v*)(msrc + row * 2048 + col);
      const unsigned w = (unsigned)x.x | ((unsigned)x.y << 8) |
                         ((unsigned)x.z << 16) | ((unsigned)x.w << 24);
      *(unsigned*)(mbits + row * 128 + (col ^ ((row & 7) << 4))) = w;
    }
    __syncthreads();

    // phase 2: gather 32 bits per entry (r17 layout; tid' == flash64r lane mapping)
    const int wv = tid >> 6, qd = (tid >> 4) & 3, m16_ = tid & 15;
    const int row = wv * 16 + m16_;
    const int swz = (row & 7) << 4;
    const unsigned char* rb = mbits + row * 128;
    unsigned d = 0;
#pragma unroll
    for (int hb = 0; hb < 2; ++hb)
#pragma unroll
      for (int grp = 0; grp < 4; ++grp) {
        const unsigned w =
            *(const unsigned*)(rb + ((hb * 64 + grp * 16 + qd * 4) ^ swz));
        const unsigned nib = (((w & 0x01010101u) * 0x01020408u) >> 24) & 0xFu;
        d |= nib << (hb * 16 + grp * 4);
      }
    mmod[mb * 256 + tid] = d;
    return;
  }

  // ---- projection: Out = X @ W^T on TWO 64-row slabs (1536 blocks) ----
  __shared__ short xt[64][72];
  __shared__ short ot[64][72];
  const int mode = bid >> 9;          // 512 blocks per mode
  const int btp = (bid & 511) * 2;    // first slab index
  const float* X;
  const float* W;
  float scale;
  if (mode == 0) { X = q; W = Wq; scale = 0.045084220f; }  // log2(e)/32 folded into Q
  else if (mode == 1) { X = k; W = Wk; scale = 1.0f; }
  else { X = v; W = Wv; scale = 1.0f; }

  const int lane = tid & 63, wave = tid >> 6;
  const int m16 = lane & 15, quad = lane >> 4;
  const int row_st = tid >> 2, seg = (tid & 3) * 16;
  const int orow = tid >> 2, opart = tid & 3;

  // hoist W fragments (pack once, reuse for both slabs)
  short8 wb[4][2];
#pragma unroll
  for (int nt = 0; nt < 4; ++nt) {
    const f32x4* wp0 = (const f32x4*)&W[(nt * 16 + m16) * 64 + quad * 8];
    const f32x4* wp1 = (const f32x4*)&W[(nt * 16 + m16) * 64 + 32 + quad * 8];
    wb[nt][0] = pack8(wp0[0], wp0[1]);
    wb[nt][1] = pack8(wp1[0], wp1[1]);
  }

  for (int sl = 0; sl < 2; ++sl) {
    const int r0 = (btp + sl) * 64;
    const f32x4* xs = (const f32x4*)(X + (r0 + row_st) * 64 + seg);
    const f32x4 x0 = xs[0], x1 = xs[1], x2 = xs[2], x3 = xs[3];
    *(short8*)&xt[row_st][seg] = pack8(x0, x1);
    *(short8*)&xt[row_st][seg + 8] = pack8(x2, x3);
    __syncthreads();

    const short8 a0 = *(const short8*)&xt[wave * 16 + m16][quad * 8];
    const short8 a1 = *(const short8*)&xt[wave * 16 + m16][32 + quad * 8];

    f32x4 acc[4];
#pragma unroll
    for (int nt = 0; nt < 4; ++nt) {
      f32x4 z = (f32x4){0.f, 0.f, 0.f, 0.f};
      z = __builtin_amdgcn_mfma_f32_16x16x32_bf16(a0, wb[nt][0], z, 0, 0, 0);
      z = __builtin_amdgcn_mfma_f32_16x16x32_bf16(a1, wb[nt][1], z, 0, 0, 0);
      acc[nt] = z;
    }

    if (mode != 2) {
#pragma unroll
      for (int nt = 0; nt < 4; ++nt)
#pragma unroll
        for (int r = 0; r < 4; ++r)
          ot[wave * 16 + quad * 4 + r][nt * 16 + m16] = f2bf(acc[nt][r] * scale);
    } else {
      // transposed + sigma'-permuted: ot[d][sigma'(key)],
      // key = wave*16 + quad*4 + r -> sigma' = quad*8 + (wave&1)*4 + r + (wave>>1)*32
#pragma unroll
      for (int nt = 0; nt < 4; ++nt)
#pragma unroll
        for (int r = 0; r < 4; ++r)
          ot[nt * 16 + m16][quad * 8 + (wave & 1) * 4 + r + (wave >> 1) * 32] =
              f2bf(acc[nt][r]);
    }
    __syncthreads();

    if (mode != 2) {
      short* dst = (mode == 0 ? Qp : Kp) + (r0 + orow) * 64 + opart * 16;
      *(short8*)&dst[0] = *(const short8*)&ot[orow][opart * 16];
      *(short8*)&dst[8] = *(const short8*)&ot[orow][opart * 16 + 8];
    } else {
      const int bh = r0 >> 11, s0 = r0 & 2047;
      short* dst = Vtp + bh * 131072 + orow * 2048 + s0 + opart * 16;
      *(short8*)&dst[0] = *(const short8*)&ot[orow][opart * 16];
      *(short8*)&dst[8] = *(const short8*)&ot[orow][opart * 16 + 8];
    }
    if (sl == 0) __syncthreads();  // ot-store LDS reads drain before next slab's xt/ot writes
  }
}

// =============== flash64r: 64 q-rows, in-register P, l via ones-MFMA ===============
// r20: UNCHANGED from r19 (noise anchor: 58.4 us in R6 run, 63.3 us in R8 run,
// same source — quantifies cross-container variance).
__global__ __launch_bounds__(256) void flash64r(const short* __restrict__ Qp,
                                                const short* __restrict__ Kp,
                                                const short* __restrict__ Vt,
                                                const unsigned* __restrict__ mmod,
                                                short* __restrict__ Ob) {
  __shared__ __attribute__((aligned(16))) short kt0[4096];
  __shared__ __attribute__((aligned(16))) short kt1[4096];
  __shared__ __attribute__((aligned(16))) short vt0[4096];
  __shared__ __attribute__((aligned(16))) short vt1[4096];
  const int tid = threadIdx.x;
  const int bid = blockIdx.x;
  const int local = bid >> 3;  // XCD-grouping on bid&7
  const int qblk = local & 31;
  const int bh = (bid & 7) * 4 + (local >> 5);
  const int q0 = qblk << 6;
  const int b = bh >> 4;
  const short* Qh = Qp + bh * 131072;
  const short* Kh = Kp + bh * 131072;
  const short* Vh = Vt + bh * 131072;
  const int lane = tid & 63, wave = tid >> 6;
  const int m16 = lane & 15, quad = lane >> 4;
  const int srow = lane >> 3, sj = (lane & 7) ^ srow;
  const int koff = m16 * 128 + ((quad ^ (m16 & 7)) * 16);
  const int koffx = koff ^ 64;
  // per-lane mask dword: table tid' = wave*64 + lane; one dword per kp (2 tiles)
  const unsigned* mq = mmod + ((b * 32 + qblk) * 16) * 256 + wave * 64 + quad * 16 + m16;

  const short onebf = (short)0x3F80;  // bf16 1.0
  const short8 ones = (short8){onebf, onebf, onebf, onebf, onebf, onebf, onebf, onebf};

  short8 aq[2];
#pragma unroll
  for (int h = 0; h < 2; ++h)
    aq[h] = *(const short8*)&Qh[(q0 + wave * 16 + m16) * 64 + h * 32 + quad * 8];

  f32x4 oaccL = (f32x4){0.f, 0.f, 0.f, 0.f};  // row-sum accumulator (l)
  f32x4 oacc[4];
#pragma unroll
  for (int dt = 0; dt < 4; ++dt) oacc[dt] = (f32x4){0.f, 0.f, 0.f, 0.f};

  // stage 64-key tile ka into (ktb, vtb); 4 glds16 per wave (+4 vmcnt)
  auto stage = [&](short* ktb, short* vtb, int ka) {
#pragma unroll
    for (int t = 0; t < 2; ++t) {
      const int crow = wave * 16 + t * 8;
      glds16(Kh + (ka * 64 + crow + srow) * 64 + sj * 8, ktb + crow * 64, lane);
      glds16(Vh + (crow + srow) * 2048 + ka * 64 + sj * 8, vtb + crow * 64, lane);
    }
  };

  // full tile: swapped QK^T -> in-register P -> PV (+ l via ones-MFMA). No LDS writes.
  auto compute = [&](const short* ktp, const short* vtp, unsigned mw, int bb) {
    const char* kb_lo = (const char*)ktp + koff;
    const char* kb_hi = (const char*)ktp + koffx;
    const char* vb_lo = (const char*)vtp + koff;
    const char* vb_hi = (const char*)vtp + koffx;
    // S^T quadrants: s[grp][r] = S[q = m16][key = grp*16 + quad*4 + r]
    f32x4 s[4];
    __builtin_amdgcn_s_setprio(1);
#pragma unroll
    for (int grp = 0; grp < 4; ++grp) {
      const short8 kb0 = *(const short8*)(kb_lo + grp * 2048);
      const short8 kb1 = *(const short8*)(kb_hi + grp * 2048);
      f32x4 z = (f32x4){0.f, 0.f, 0.f, 0.f};
      z = __builtin_amdgcn_mfma_f32_16x16x32_bf16(kb0, aq[0], z, 0, 0, 0);
      z = __builtin_amdgcn_mfma_f32_16x16x32_bf16(kb1, aq[1], z, 0, 0, 0);
      s[grp] = z;
    }
    __builtin_amdgcn_s_setprio(0);

    // p = exp2(s) & mask-bit (all 16 p's belong to q = m16)
    float p[4][4];
#pragma unroll
    for (int grp = 0; grp < 4; ++grp)
#pragma unroll
      for (int r = 0; r < 4; ++r)
        p[grp][r] = fand(fexp2(s[grp][r]), bmask(mw, bb + grp * 4 + r));

    // pack P into the PV A-fragments directly (sigma' makes these the lane's slots)
    int4v t0, t1;
    t0.x = pktr(p[0][0], p[0][1]);
    t0.y = pktr(p[0][2], p[0][3]);
    t0.z = pktr(p[1][0], p[1][1]);
    t0.w = pktr(p[1][2], p[1][3]);
    t1.x = pktr(p[2][0], p[2][1]);
    t1.y = pktr(p[2][2], p[2][3]);
    t1.z = pktr(p[3][0], p[3][1]);
    t1.w = pktr(p[3][2], p[3][3]);
    const short8 ap0 = __builtin_bit_cast(short8, t0);
    const short8 ap1 = __builtin_bit_cast(short8, t1);

    // O += P V; l += P·1 (matrix pipe; no LDS dep -> issues while vb reads land)
    __builtin_amdgcn_s_setprio(1);
    oaccL = __builtin_amdgcn_mfma_f32_16x16x32_bf16(ap0, ones, oaccL, 0, 0, 0);
    oaccL = __builtin_amdgcn_mfma_f32_16x16x32_bf16(ap1, ones, oaccL, 0, 0, 0);
#pragma unroll
    for (int dt = 0; dt < 4; ++dt) {
      const short8 vb0 = *(const short8*)(vb_lo + dt * 2048);
      const short8 vb1 = *(const short8*)(vb_hi + dt * 2048);
      f32x4 z = oacc[dt];
      z = __builtin_amdgcn_mfma_f32_16x16x32_bf16(ap0, vb0, z, 0, 0, 0);
      z = __builtin_amdgcn_mfma_f32_16x16x32_bf16(ap1, vb1, z, 0, 0, 0);
      oacc[dt] = z;
    }
    __builtin_amdgcn_s_setprio(0);
  };

  // ---- prologue: mask for kp=0, both stages; first waitA covers aq+M0+S0 ----
  unsigned mw = mq[0];
  stage(kt0, vt0, 0);
  stage(kt1, vt1, 1);

  for (int kk = 0; kk < 15; ++kk) {
    const unsigned mwn = mq[(kk + 1) * 256];
    // tile A = 2kk (buf0): drain M(kk)+S(2kk); newer = S(2kk+1)[4] + M(kk+1)[1]
    asm volatile("s_waitcnt vmcnt(5)" ::: "memory");
    __builtin_amdgcn_s_barrier();
    compute(kt0, vt0, mw, 0);
    __builtin_amdgcn_s_barrier();  // done reading buf0
    stage(kt0, vt0, 2 * kk + 2);
    // tile B = 2kk+1 (buf1): drain S(2kk+1); newer = M(kk+1)[1] + S(2kk+2)[4]
    asm volatile("s_waitcnt vmcnt(5)" ::: "memory");
    __builtin_amdgcn_s_barrier();
    compute(kt1, vt1, mw, 16);
    __builtin_amdgcn_s_barrier();  // done reading buf1
    stage(kt1, vt1, 2 * kk + 3);
    mw = mwn;
  }
  // peeled kk=15: outstanding [M15(1), S30(4), S31(4)]
  asm volatile("s_waitcnt vmcnt(4)" ::: "memory");
  __builtin_amdgcn_s_barrier();
  compute(kt0, vt0, mw, 0);
  asm volatile("s_waitcnt vmcnt(0)" ::: "memory");
  __builtin_amdgcn_s_barrier();
  compute(kt1, vt1, mw, 16);

  // ---- epilogue ----
  // l[q = quad*4 + r] = oaccL[r] on every lane (ones-B makes all 16 cols equal)
  float linv[4];
#pragma unroll
  for (int r = 0; r < 4; ++r) linv[r] = 1.0f / oaccL[r];

  // normalize, write O (bf16) into kt0 (swizzled; wave-private rows — safe: all
  // cross-wave kt0 reads finished before the barrier preceding compute(kt1))
  char* const ptB = (char*)kt0;
#pragma unroll
  for (int r = 0; r < 4; ++r) {
    const int row = wave * 16 + quad * 4 + r;
#pragma unroll
    for (int dt = 0; dt < 4; ++dt)
      *(short*)(ptB + row * 128 + ((dt * 32 + m16 * 2) ^ ((row & 7) << 4))) =
          f2bf(oacc[dt][r] * linv[r]);
  }
  asm volatile("s_waitcnt lgkmcnt(0)" ::: "memory");  // same-wave rows: no barrier

  // coalesced O store (rows partitioned within the wave)
  const int orow = lane >> 2, opart = lane & 3;
  const int prow = wave * 16 + orow;
  const int oswz = (orow & 7) << 4;
  short* og = Ob + (bh * 2048 + q0 + prow) * 64 + opart * 16;
  *(short8*)&og[0] = *(const short8*)(ptB + prow * 128 + ((opart * 32) ^ oswz));
  *(short8*)&og[8] = *(const short8*)(ptB + prow * 128 + ((opart * 32 + 16) ^ oswz));
}

// =============== outproj: out = Ob @ Wo^T + bo, 64x128 tiles, pipelined ===============
// r20: LDS-staged coalesced epilogue. Main loop unchanged (glds16, row-XOR swizzle,
// double-buffer, counted vmcnt(6), peel 6/0). LDS now one flat 48KB array; after the
// final barrier, bytes [0,32768) (= at0+at1+bt0 regions, all dead) stage the 64x128
// f32 output tile, then 8 f32x4 stores/thread (512B contiguous per 32-lane row,
// full-line writes) replace 16 scalar dword stores/lane.
__global__ __launch_bounds__(256) void outproj(const short* __restrict__ Ob,
                                               const short* __restrict__ Wob,
                                               const float* __restrict__ bo,
                                               float* __restrict__ out) {
  __shared__ __attribute__((aligned(16))) short lds[24576];  // 48 KB
  short* const at0 = lds;
  short* const at1 = lds + 4096;
  short* const bt0 = lds + 8192;
  short* const bt1 = lds + 16384;
  const int tid = threadIdx.x;
  const int bid = blockIdx.x;
  const int ct = bid >> 6, rt = bid & 63;  // ct-major: consecutive bids share Wob slab
  const int r0 = rt * 64, c0 = ct * 128;
  const int lane = tid & 63, wave = tid >> 6;
  const int mr = (wave >> 1) * 32, nc = (wave & 1) * 64;
  const int m16 = lane & 15, quad = lane >> 4;
  const int srow = lane >> 3, sj = (lane & 7) ^ srow;
  const int mswz = (m16 & 7) << 4;

  f32x4 acc[2][4];
#pragma unroll
  for (int mt = 0; mt < 2; ++mt)
#pragma unroll
    for (int nt = 0; nt < 4; ++nt) acc[mt][nt] = (f32x4){0.f, 0.f, 0.f, 0.f};

  // stage one K-slab (64 cols) of A (64 rows) + B (128 rows): 6 glds16/wave
  auto stageK = [&](short* atb, short* btb, int kc) {
#pragma unroll
    for (int t = 0; t < 2; ++t) {
      const int crow = wave * 16 + t * 8;
      glds16(Ob + (r0 + crow + srow) * 1024 + kc * 64 + sj * 8, atb + crow * 64, lane);
    }
#pragma unroll
    for (int t = 0; t < 4; ++t) {
      const int crow = wave * 32 + t * 8;
      glds16(Wob + (c0 + crow + srow) * 1024 + kc * 64 + sj * 8, btb + crow * 64, lane);
    }
  };

  auto computeK = [&](const short* atp, const short* btp) {
    const char* atB = (const char*)atp;
    const char* btB = (const char*)btp;
#pragma unroll
    for (int kh = 0; kh < 2; ++kh) {
      short8 af[2], bf[4];
#pragma unroll
      for (int i = 0; i < 2; ++i)
        af[i] = *(const short8*)(atB + (mr + i * 16 + m16) * 128 +
                                 ((kh * 64 + quad * 16) ^ mswz));
#pragma unroll
      for (int j = 0; j < 4; ++j)
        bf[j] = *(const short8*)(btB + (nc + j * 16 + m16) * 128 +
                                 ((kh * 64 + quad * 16) ^ mswz));
      __builtin_amdgcn_s_setprio(1);
#pragma unroll
      for (int mt = 0; mt < 2; ++mt)
#pragma unroll
        for (int nt = 0; nt < 4; ++nt)
          acc[mt][nt] = __builtin_amdgcn_mfma_f32_16x16x32_bf16(af[mt], bf[nt],
                                                                acc[mt][nt], 0, 0, 0);
      __builtin_amdgcn_s_setprio(0);
    }
  };

  stageK(at0, bt0, 0);
  stageK(at1, bt1, 1);
  for (int kc = 0; kc < 14; ++kc) {
    short* atb = (kc & 1) ? at1 : at0;
    short* btb = (kc & 1) ? bt1 : bt0;
    asm volatile("s_waitcnt vmcnt(6)" ::: "memory");  // drain S(kc), keep S(kc+1)
    __builtin_amdgcn_s_barrier();
    computeK(atb, btb);
    __builtin_amdgcn_s_barrier();  // done reading this buffer
    stageK(atb, btb, kc + 2);
  }
  // peel kc=14, 15: in flight [S14(6), S15(6)]
  asm volatile("s_waitcnt vmcnt(6)" ::: "memory");
  __builtin_amdgcn_s_barrier();
  computeK(at0, bt0);
  asm volatile("s_waitcnt vmcnt(0)" ::: "memory");
  __builtin_amdgcn_s_barrier();
  computeK(at1, bt1);
  __builtin_amdgcn_s_barrier();  // all bt1/at1 LDS reads done; [0,32K) free for staging

  // ---- epilogue: stage 64x128 f32 tile in LDS, then coalesced f32x4 stores ----
  char* const st = (char*)lds;  // rows: 512 B each, plain layout (one-time cost)
#pragma unroll
  for (int nt = 0; nt < 4; ++nt) {
    const int col = nc + nt * 16 + m16;
    const float bias = bo[c0 + col];
#pragma unroll
    for (int mt = 0; mt < 2; ++mt)
#pragma unroll
      for (int rr2 = 0; rr2 < 4; ++rr2)
        *(float*)(st + (mr + mt * 16 + quad * 4 + rr2) * 512 + col * 4) =
            acc[mt][nt][rr2] + bias;
  }
  __syncthreads();

#pragma unroll
  for (int i = 0; i < 8; ++i) {
    const int idx = tid + i * 256;      // f32x4 index in the 64x128 tile
    const int row = idx >> 5, col4 = idx & 31;
    *(f32x4*)&out[(r0 + row) * 1024 + c0 + col4 * 4] =
        *(const f32x4*)(st + row * 512 + col4 * 16);
  }
}

// ---------------- launch ----------------
extern "C" void kernel_launch(void* const* d_in, const int* in_sizes, int n_in,
                              void* d_out, int out_size, void* d_ws, size_t ws_size,
                              hipStream_t stream) {
  const float* query = (const float*)d_in[0];
  const float* key = (const float*)d_in[1];
  const float* value = (const float*)d_in[2];
  const int* mask = (const int*)d_in[3];
  const float* Wq = (const float*)d_in[4];
  const float* Wk = (const float*)d_in[5];
  const float* Wv = (const float*)d_in[6];
  const float* Wo = (const float*)d_in[7];
  const float* bo = (const float*)d_in[8];
  float* out = (float*)d_out;

  char* ws = (char*)d_ws;
  short* Qp = (short*)(ws);                       // 8 MB
  short* Kp = (short*)(ws + 8388608);             // 8 MB
  short* Vt = (short*)(ws + 16777216);            // 8 MB
  short* Ob = (short*)(ws + 25165824);            // 8 MB (flash output, distinct from Qp)
  short* Wob = (short*)(ws + 41943040);           // 2 MB
  unsigned* mmod = (unsigned*)(ws + 44564480);    // 1 MB

  prep<<<2816, 256, 0, stream>>>(query, key, value, Wq, Wk, Wv, Wo, mask,
                                 Qp, Kp, Vt, Wob, mmod);
  flash64r<<<1024, 256, 0, stream>>>(Qp, Kp, Vt, mmod, Ob);
  outproj<<<512, 256, 0, stream>>>(Ob, Wob, bo, out);
}